// Round 5
// baseline (347.581 us; speedup 1.0000x reference)
//
#include <hip/hip_runtime.h>
#include <math.h>
#include <stdint.h>

#define D 128          // feature dim (d_in = d_h = 128)
#define SCAN_CHUNK 2048
#define LDA 136        // LDS row stride in shorts (+8 pad: 16-way -> 2-way bank conflict)
#define AGG_BLOCKS 4096   // 8 XCD slots x 512 blocks; per quarter-group: 1024 blocks = 4096 waves
#define AGG_STRIDE 4096   // waves per quarter-group

typedef __attribute__((ext_vector_type(8))) short v8s;   // 8 bf16 (4 VGPRs)
typedef __attribute__((ext_vector_type(4))) float v4f;   // MFMA accumulator

// bf16 round-to-nearest-even
static __device__ __forceinline__ uint16_t f2bf(float f) {
    uint32_t u = __float_as_uint(f);
    u = (u + 0x7fff + ((u >> 16) & 1)) >> 16;
    return (uint16_t)u;
}
static __device__ __forceinline__ float bf2f(uint16_t h) { return __uint_as_float((uint32_t)h << 16); }
static __device__ __forceinline__ float bf_lo(uint32_t u) { return __uint_as_float(u << 16); }
static __device__ __forceinline__ float bf_hi(uint32_t u) { return __uint_as_float(u & 0xffff0000u); }

// ---------------- count + rank + W-pack (fused, independent work) ----------------
// rank[e] = edge's slot within its target bucket (atomicAdd return) -> fill has NO atomics.

__global__ void countpack_kernel(const int* __restrict__ col, int* __restrict__ cnt,
                                 int* __restrict__ rnk, int E,
                                 const float* __restrict__ W1, const float* __restrict__ W2,
                                 uint16_t* __restrict__ Wh, uint16_t* __restrict__ Wl) {
    int tid = blockIdx.x * blockDim.x + threadIdx.x;
    if (tid < 2 * 16384) {
        int layer = tid >> 14;
        int li = tid & 16383;
        int j = li & 7, lane = (li >> 3) & 63, f = li >> 9;
        int kstep = f >> 3, tile = f & 7;
        int k = kstep * 32 + ((lane >> 4) * 8) + j;
        int nn = tile * 16 + (lane & 15);
        const float* W = layer ? W2 : W1;
        float v = W[k * 128 + nn];
        uint16_t h = f2bf(v);
        Wh[tid] = h;
        Wl[tid] = f2bf(v - bf2f(h));
    }
    if (tid < E) rnk[tid] = atomicAdd(&cnt[col[tid]], 1);
}

// ---------------- scan phase A: per-chunk sums (+ fused dinv + P init) ----------------
// Multi-block, coalesced. (Single-block variant measured 134 us @0.17% occupancy — do not revisit.)

__global__ __launch_bounds__(256) void scanA_kernel(const int* __restrict__ cnt,
                                                    int* __restrict__ bsum,
                                                    float* __restrict__ dinv,
                                                    const float* __restrict__ bfc,
                                                    float* __restrict__ P1,
                                                    float* __restrict__ P2, int n) {
    __shared__ int wsum[4];
    int b = blockIdx.x, t = threadIdx.x;
    int base = b * SCAN_CHUNK;
    float4 bb = *(const float4*)bfc;
    int s = 0;
#pragma unroll
    for (int k = 0; k < SCAN_CHUNK / 256; k++) {
        int i = base + k * 256 + t;
        if (i < n) {
            int c = cnt[i];
            s += c;
            dinv[i] = rsqrtf((float)c + 1.0f);
            ((float4*)P1)[i] = bb;                                   // bias init for atomic accum
            ((float4*)P2)[i] = make_float4(0.f, 0.f, 0.f, 0.f);
        }
    }
#pragma unroll
    for (int off = 32; off > 0; off >>= 1) s += __shfl_xor(s, off, 64);
    if ((t & 63) == 0) wsum[t >> 6] = s;
    __syncthreads();
    if (t == 0) bsum[b] = wsum[0] + wsum[1] + wsum[2] + wsum[3];
}

// ---------------- scan phase C: local exclusive scan, block bases inlined ----------------

__global__ __launch_bounds__(256) void scanC_kernel(const int* __restrict__ cnt,
                                                    const int* __restrict__ bsum,
                                                    int* __restrict__ offs, int n, int nb) {
    __shared__ int stage[SCAN_CHUNK];
    __shared__ int res[SCAN_CHUNK];
    __shared__ int tsum[256];
    __shared__ int sb[64];
    int b = blockIdx.x, t = threadIdx.x;
    if (t < 64) {
        int v = (t < nb) ? bsum[t] : 0;
        int inc = v;
#pragma unroll
        for (int off = 1; off < 64; off <<= 1) {
            int u = __shfl_up(inc, off, 64);
            if (t >= off) inc += u;
        }
        sb[t] = inc;
    }
    int base = b * SCAN_CHUNK;
#pragma unroll
    for (int k = 0; k < SCAN_CHUNK / 256; k++) {
        int i = base + k * 256 + t;
        stage[k * 256 + t] = (i < n) ? cnt[i] : 0;
    }
    __syncthreads();
    int my = 0;
#pragma unroll
    for (int j = 0; j < 8; j++) my += stage[t * 8 + j];
    tsum[t] = my;
    __syncthreads();
    for (int off = 1; off < 256; off <<= 1) {
        int v = (t >= off) ? tsum[t - off] : 0;
        __syncthreads();
        tsum[t] += v;
        __syncthreads();
    }
    int bbase = (b == 0) ? 0 : sb[b - 1];
    int run = tsum[t] - my + bbase;
#pragma unroll
    for (int j = 0; j < 8; j++) {
        res[t * 8 + j] = run;
        run += stage[t * 8 + j];
    }
    __syncthreads();
#pragma unroll
    for (int k = 0; k < SCAN_CHUNK / 256; k++) {
        int i = base + k * 256 + t;
        if (i < n) offs[i] = res[k * 256 + t];
    }
    if (b == gridDim.x - 1 && t == 0) offs[n] = sb[nb - 1];
}

// ---------------- MFMA GEMM body (4 waves) ----------------
// split-bf16 (Markidis): A@W ~= Ah@Wh + Ah@Wl + Al@Wh; result pre-scaled by dinv.
// C-write is QUARTER-BLOCKED: Cb[q][gr][32] bf16 (q = feature/32) so the downstream
// gather reads a 3.2 MB table per quarter (fits one XCD's 4 MiB L2).

static __device__ __forceinline__ void gemm_body(const uint16_t Ah[][LDA],
                                                 const uint16_t Al[][LDA],
                                                 const uint16_t* __restrict__ Wph,
                                                 const uint16_t* __restrict__ Wpl,
                                                 const float* __restrict__ dinv,
                                                 uint16_t* __restrict__ Cb,
                                                 int base_row, int M, int t) {
    int lane = t & 63, w = t >> 6;
    int m_l = lane & 15, quad = lane >> 4;
    int arow = w * 16 + m_l;

    v4f acc[8];
#pragma unroll
    for (int i = 0; i < 8; i++) acc[i] = (v4f){0.f, 0.f, 0.f, 0.f};

#pragma unroll
    for (int ks = 0; ks < 4; ks++) {
        v8s ah = *(const v8s*)&Ah[arow][ks * 32 + quad * 8];
        v8s al = *(const v8s*)&Al[arow][ks * 32 + quad * 8];
#pragma unroll
        for (int ti = 0; ti < 8; ti++) {
            int f = ks * 8 + ti;
            v8s bh = *(const v8s*)(Wph + ((size_t)(f * 64 + lane)) * 8);
            v8s bl = *(const v8s*)(Wpl + ((size_t)(f * 64 + lane)) * 8);
            acc[ti] = __builtin_amdgcn_mfma_f32_16x16x32_bf16(al, bh, acc[ti], 0, 0, 0);
            acc[ti] = __builtin_amdgcn_mfma_f32_16x16x32_bf16(ah, bl, acc[ti], 0, 0, 0);
            acc[ti] = __builtin_amdgcn_mfma_f32_16x16x32_bf16(ah, bh, acc[ti], 0, 0, 0);
        }
    }

    int rbase = base_row + w * 16 + quad * 4;
#pragma unroll
    for (int reg = 0; reg < 4; reg++) {
        int gr = rbase + reg;
        if (gr < M) {
            float di = dinv[gr];
#pragma unroll
            for (int ti = 0; ti < 8; ti++) {
                // feature = ti*16 + m_l; quarter = ti>>1; within-quarter = (ti&1)*16 + m_l
                Cb[(((size_t)(ti >> 1)) * M + gr) * 32 + (ti & 1) * 16 + m_l] =
                    f2bf(di * acc[ti][reg]);
            }
        }
    }
}

// ---------------- fused: CSR fill (block-role split) + layer-1 GEMM ----------------

__global__ __launch_bounds__(256) void fillgemm_kernel(const int* __restrict__ row,
                                                       const int* __restrict__ col,
                                                       const int* __restrict__ rnk,
                                                       const int* __restrict__ offs,
                                                       int* __restrict__ adj, int E,
                                                       const float* __restrict__ A,
                                                       const uint16_t* __restrict__ Wph,
                                                       const uint16_t* __restrict__ Wpl,
                                                       const float* __restrict__ dinv,
                                                       uint16_t* __restrict__ Cb, int M,
                                                       int nbG) {
    __shared__ uint16_t Ah[64][LDA];
    __shared__ uint16_t Al[64][LDA];
    int t = threadIdx.x;

    if (blockIdx.x >= nbG) {   // ---- fill role (atomic-free scatter) ----
        int e = (blockIdx.x - nbG) * 256 + t;
        if (e < E) adj[offs[col[e]] + rnk[e]] = row[e];
        return;
    }

    // ---- gemm role: stage x-tile as split bf16, then MFMA ----
    int base_row = blockIdx.x * 64;
#pragma unroll
    for (int kk = 0; kk < 8; kk++) {
        int idx = kk * 256 + t;
        int r = idx >> 5;
        int c4 = idx & 31;
        int gr = base_row + r;
        float4 f = (gr < M) ? *(const float4*)(A + (size_t)gr * D + c4 * 4)
                            : make_float4(0.f, 0.f, 0.f, 0.f);
        uint16_t h0 = f2bf(f.x), h1 = f2bf(f.y), h2 = f2bf(f.z), h3 = f2bf(f.w);
        uint16_t l0 = f2bf(f.x - bf2f(h0)), l1 = f2bf(f.y - bf2f(h1));
        uint16_t l2 = f2bf(f.z - bf2f(h2)), l3 = f2bf(f.w - bf2f(h3));
        *(ushort4*)&Ah[r][c4 * 4] = make_ushort4(h0, h1, h2, h3);
        *(ushort4*)&Al[r][c4 * 4] = make_ushort4(l0, l1, l2, l3);
    }
    __syncthreads();
    gemm_body(Ah, Al, Wph, Wpl, dinv, Cb, base_row, M, t);
}

// ---------------- layer-2 GEMM: reads quarter-blocked f32 h1q ----------------

__global__ __launch_bounds__(256) void gemm2_kernel(const float* __restrict__ h1q,
                                                    const uint16_t* __restrict__ Wph,
                                                    const uint16_t* __restrict__ Wpl,
                                                    const float* __restrict__ dinv,
                                                    uint16_t* __restrict__ Cb, int M) {
    __shared__ uint16_t Ah[64][LDA];
    __shared__ uint16_t Al[64][LDA];
    int t = threadIdx.x;
    int base_row = blockIdx.x * 64;
#pragma unroll
    for (int kk = 0; kk < 8; kk++) {
        int idx = kk * 256 + t;
        int r = idx >> 5;
        int c4 = idx & 31;           // feature block: quarter qq = c4>>3, chunk cc = c4&7
        int gr = base_row + r;
        int qq = c4 >> 3, cc = c4 & 7;
        float4 f = (gr < M) ? ((const float4*)h1q)[((size_t)qq * M + gr) * 8 + cc]
                            : make_float4(0.f, 0.f, 0.f, 0.f);
        uint16_t h0 = f2bf(f.x), h1 = f2bf(f.y), h2 = f2bf(f.z), h3 = f2bf(f.w);
        uint16_t l0 = f2bf(f.x - bf2f(h0)), l1 = f2bf(f.y - bf2f(h1));
        uint16_t l2 = f2bf(f.z - bf2f(h2)), l3 = f2bf(f.w - bf2f(h3));
        *(ushort4*)&Ah[r][c4 * 4] = make_ushort4(h0, h1, h2, h3);
        *(ushort4*)&Al[r][c4 * 4] = make_ushort4(l0, l1, l2, l3);
    }
    __syncthreads();
    gemm_body(Ah, Al, Wph, Wpl, dinv, Cb, base_row, M, t);
}

// ---------------- quartered aggregation, layer 1 ----------------
// blockIdx%8 -> XCD slot; quarter q = (b&7)>>1 so each quarter runs on a 2-XCD pair whose
// L2s hold that quarter's 3.2 MB gather table. One wave per node (grid-stride); each load
// instruction fetches 4 edges x 64 B (lane = 16*e + c). Writes h1q[4][n][32] f32.

__global__ __launch_bounds__(256) void aggq1_kernel(const uint32_t* __restrict__ xwbq,
                                                    const int* __restrict__ adj,
                                                    const int* __restrict__ offs,
                                                    const float* __restrict__ dinv,
                                                    const float* __restrict__ bias,
                                                    float* __restrict__ h1q, int n) {
    int b = blockIdx.x, t = threadIdx.x;
    int q = (b & 7) >> 1;
    int sub = ((b >> 3) << 1) + (b & 1);
    int w = t >> 6, lane = t & 63;
    int c = lane & 15, e = lane >> 4;
    const uint32_t* tbl = xwbq + (size_t)q * n * 16;
    float2 bv = ((const float2*)bias)[q * 16 + c];
    for (int i = sub * 4 + w; i < n; i += AGG_STRIDE) {
        uint32_t su = tbl[(size_t)i * 16 + c];
        float a0 = (e == 0) ? bf_lo(su) : 0.f;
        float a1 = (e == 0) ? bf_hi(su) : 0.f;
        int j = offs[i], en = offs[i + 1];
        for (; j + 7 < en; j += 8) {
            int i1 = adj[j + e], i2 = adj[j + 4 + e];
            uint32_t u1 = tbl[(size_t)i1 * 16 + c];
            uint32_t u2 = tbl[(size_t)i2 * 16 + c];
            a0 += bf_lo(u1) + bf_lo(u2);
            a1 += bf_hi(u1) + bf_hi(u2);
        }
        for (; j + 3 < en; j += 4) {
            int i1 = adj[j + e];
            uint32_t u1 = tbl[(size_t)i1 * 16 + c];
            a0 += bf_lo(u1); a1 += bf_hi(u1);
        }
        if (j + e < en) {
            uint32_t u1 = tbl[(size_t)adj[j + e] * 16 + c];
            a0 += bf_lo(u1); a1 += bf_hi(u1);
        }
        // reduce across the 4 edge-subgroups (lanes c, c+16, c+32, c+48)
        a0 += __shfl_xor(a0, 16, 64); a0 += __shfl_xor(a0, 32, 64);
        a1 += __shfl_xor(a1, 16, 64); a1 += __shfl_xor(a1, 32, 64);
        float di = dinv[i];
        float o0 = fmaxf(fmaf(di, a0, bv.x), 0.f);
        float o1 = fmaxf(fmaf(di, a1, bv.y), 0.f);
        if (lane < 16)
            ((float2*)h1q)[((size_t)q * n + i) * 16 + c] = make_float2(o0, o1);
    }
}

// ---------------- quartered aggregation, layer 2 + classifier partials ----------------
// Same gather; then partial P1/P2 (classifier dot-products restricted to this quarter's
// 32 features) reduced across the 16 c-lanes and atomically added into P1/P2
// (P1 pre-initialized to bfc, P2 to 0, in scanA).

__global__ __launch_bounds__(256) void aggq2_kernel(const uint32_t* __restrict__ xwbq,
                                                    const int* __restrict__ adj,
                                                    const int* __restrict__ offs,
                                                    const float* __restrict__ dinv,
                                                    const float* __restrict__ bias,
                                                    const float* __restrict__ Wfc,
                                                    float* __restrict__ P1,
                                                    float* __restrict__ P2, int n) {
    int b = blockIdx.x, t = threadIdx.x;
    int q = (b & 7) >> 1;
    int sub = ((b >> 3) << 1) + (b & 1);
    int w = t >> 6, lane = t & 63;
    int c = lane & 15, e = lane >> 4;
    const uint32_t* tbl = xwbq + (size_t)q * n * 16;
    float2 bv = ((const float2*)bias)[q * 16 + c];
    const float4* W4 = (const float4*)Wfc;          // Wfc is [256][4] row-major
    float4 w1a = W4[q * 32 + 2 * c];
    float4 w1b = W4[q * 32 + 2 * c + 1];
    float4 w2a = W4[128 + q * 32 + 2 * c];
    float4 w2b = W4[128 + q * 32 + 2 * c + 1];
    for (int i = sub * 4 + w; i < n; i += AGG_STRIDE) {
        uint32_t su = tbl[(size_t)i * 16 + c];
        float a0 = (e == 0) ? bf_lo(su) : 0.f;
        float a1 = (e == 0) ? bf_hi(su) : 0.f;
        int j = offs[i], en = offs[i + 1];
        for (; j + 7 < en; j += 8) {
            int i1 = adj[j + e], i2 = adj[j + 4 + e];
            uint32_t u1 = tbl[(size_t)i1 * 16 + c];
            uint32_t u2 = tbl[(size_t)i2 * 16 + c];
            a0 += bf_lo(u1) + bf_lo(u2);
            a1 += bf_hi(u1) + bf_hi(u2);
        }
        for (; j + 3 < en; j += 4) {
            int i1 = adj[j + e];
            uint32_t u1 = tbl[(size_t)i1 * 16 + c];
            a0 += bf_lo(u1); a1 += bf_hi(u1);
        }
        if (j + e < en) {
            uint32_t u1 = tbl[(size_t)adj[j + e] * 16 + c];
            a0 += bf_lo(u1); a1 += bf_hi(u1);
        }
        a0 += __shfl_xor(a0, 16, 64); a0 += __shfl_xor(a0, 32, 64);
        a1 += __shfl_xor(a1, 16, 64); a1 += __shfl_xor(a1, 32, 64);
        float di = dinv[i];
        float o0 = fmaxf(fmaf(di, a0, bv.x), 0.f);
        float o1 = fmaxf(fmaf(di, a1, bv.y), 0.f);
        // classifier partials for this quarter's 2 features per lane
        float p0 = fmaf(o0, w1a.x, o1 * w1b.x), p1 = fmaf(o0, w1a.y, o1 * w1b.y);
        float p2 = fmaf(o0, w1a.z, o1 * w1b.z), p3 = fmaf(o0, w1a.w, o1 * w1b.w);
        float q0 = fmaf(o0, w2a.x, o1 * w2b.x), q1 = fmaf(o0, w2a.y, o1 * w2b.y);
        float q2 = fmaf(o0, w2a.z, o1 * w2b.z), q3 = fmaf(o0, w2a.w, o1 * w2b.w);
#pragma unroll
        for (int off = 1; off < 16; off <<= 1) {
            p0 += __shfl_xor(p0, off, 64);
            p1 += __shfl_xor(p1, off, 64);
            p2 += __shfl_xor(p2, off, 64);
            p3 += __shfl_xor(p3, off, 64);
            q0 += __shfl_xor(q0, off, 64);
            q1 += __shfl_xor(q1, off, 64);
            q2 += __shfl_xor(q2, off, 64);
            q3 += __shfl_xor(q3, off, 64);
        }
        if (lane == 0) {
            atomicAdd(&P1[(size_t)i * 4 + 0], p0);
            atomicAdd(&P1[(size_t)i * 4 + 1], p1);
            atomicAdd(&P1[(size_t)i * 4 + 2], p2);
            atomicAdd(&P1[(size_t)i * 4 + 3], p3);
            atomicAdd(&P2[(size_t)i * 4 + 0], q0);
            atomicAdd(&P2[(size_t)i * 4 + 1], q1);
            atomicAdd(&P2[(size_t)i * 4 + 2], q2);
            atomicAdd(&P2[(size_t)i * 4 + 3], q3);
        }
    }
}

// ---------------- edge classifier: one THREAD per edge ----------------

__global__ __launch_bounds__(256) void edge2_kernel(const int* __restrict__ row,
                                                    const int* __restrict__ col,
                                                    const float* __restrict__ P1,
                                                    const float* __restrict__ P2,
                                                    float* __restrict__ out, int E) {
    int e = blockIdx.x * blockDim.x + threadIdx.x;
    if (e >= E) return;
    int r = row[e], c = col[e];
    float4 a = ((const float4*)P1)[r];
    float4 b = ((const float4*)P2)[c];
    float sx = a.x + b.x, sy = a.y + b.y, sz = a.z + b.z, sw = a.w + b.w;
    float m = fmaxf(fmaxf(sx, sy), fmaxf(sz, sw));
    float e0 = expf(sx - m), e1 = expf(sy - m), e2 = expf(sz - m), e3 = expf(sw - m);
    float lse = m + logf(e0 + e1 + e2 + e3);
    *(float4*)(out + (size_t)e * 4) = make_float4(sx - lse, sy - lse, sz - lse, sw - lse);
}

// ---------------- launch ----------------

extern "C" void kernel_launch(void* const* d_in, const int* in_sizes, int n_in,
                              void* d_out, int out_size, void* d_ws, size_t ws_size,
                              hipStream_t stream) {
    const float* x   = (const float*)d_in[0];
    const int*   ei  = (const int*)d_in[1];
    const float* W1  = (const float*)d_in[2];
    const float* b1  = (const float*)d_in[3];
    const float* W2  = (const float*)d_in[4];
    const float* b2  = (const float*)d_in[5];
    const float* Wfc = (const float*)d_in[6];
    const float* bfc = (const float*)d_in[7];
    float* out = (float*)d_out;

    int n = in_sizes[0] / D;        // 50000
    int E = in_sizes[1] / 2;        // 600000
    const int* row = ei;            // edge_index[0]
    const int* col = ei + E;        // edge_index[1]

    int nbScan = (n + SCAN_CHUNK - 1) / SCAN_CHUNK;   // 25

    // workspace layout (all segments 16B-aligned)
    uint16_t* xwb  = (uint16_t*)d_ws;                    // [4][n][32] bf16 (layer-1 xW, dinv-prescaled)
    uint16_t* xwb2 = xwb + (size_t)n * D;                // [4][n][32] bf16 (layer-2 xW, dinv-prescaled)
    float*    h1q  = (float*)(xwb2 + (size_t)n * D);     // [4][n][32] f32 (layer-1 output)
    int*      cnt  = (int*)(h1q + (size_t)n * D);        // n
    int*      offs = cnt + n;                            // n+1 (+pad)
    int*      bsum = offs + (n + 4);                     // 64
    int*      adj  = bsum + 64;                          // E
    int*      rnk  = adj + E;                            // E (edge rank within bucket)
    float*    dinv = (float*)(rnk + E);                  // n
    uint16_t* Wph  = (uint16_t*)(dinv + n);              // 2*16384 (layer-major)
    uint16_t* Wpl  = Wph + 2 * 16384;                    // 2*16384
    float*    P1   = (float*)(Wpl + 2 * 16384);          // n*4
    float*    P2   = P1 + (size_t)n * 4;                 // n*4

    int nb_e = (E + 255) / 256;
    int nbG  = (n + 63) / 64;

    // CSR count (+ W pack; rank captured from atomicAdd return)
    hipMemsetAsync(cnt, 0, (size_t)n * sizeof(int), stream);
    countpack_kernel<<<nb_e, 256, 0, stream>>>(col, cnt, rnk, E, W1, W2, Wph, Wpl);
    scanA_kernel<<<nbScan, 256, 0, stream>>>(cnt, bsum, dinv, bfc, P1, P2, n);
    scanC_kernel<<<nbScan, 256, 0, stream>>>(cnt, bsum, offs, n, nbScan);

    // fill (CSR scatter) runs concurrently with layer-1 GEMM in one grid
    fillgemm_kernel<<<nbG + nb_e, 256, 0, stream>>>(row, col, rnk, offs, adj, E,
                                                    x, Wph, Wpl, dinv, xwb, n, nbG);

    // layer-1 aggregation: quartered, XCD-pinned gather from L2-resident 3.2 MB table
    aggq1_kernel<<<AGG_BLOCKS, 256, 0, stream>>>((const uint32_t*)xwb, adj, offs, dinv, b1,
                                                 h1q, n);

    // layer-2 GEMM (reads quarter-blocked h1q, writes quarter-blocked xwb2)
    gemm2_kernel<<<nbG, 256, 0, stream>>>(h1q, Wph + 16384, Wpl + 16384, dinv, xwb2, n);

    // layer-2 aggregation + classifier partials (atomic accumulation into P1/P2)
    aggq2_kernel<<<AGG_BLOCKS, 256, 0, stream>>>((const uint32_t*)xwb2, adj, offs, dinv, b2,
                                                 Wfc, P1, P2, n);

    // edge classifier
    edge2_kernel<<<nb_e, 256, 0, stream>>>(row, col, P1, P2, out, E);
}

// Round 6
// 254.183 us; speedup vs baseline: 1.3674x; 1.3674x over previous
//
#include <hip/hip_runtime.h>
#include <math.h>
#include <stdint.h>

#define D 128          // feature dim (d_in = d_h = 128)
#define SCAN_CHUNK 2048
#define LDA 136        // LDS row stride in shorts (+8 pad: 16-way -> 2-way bank conflict)
#define AGG_BLOCKS 4096   // 8 XCD slots x 512; per quarter: 1024 blocks = 4096 waves x 4 nodes

typedef __attribute__((ext_vector_type(8))) short v8s;   // 8 bf16 (4 VGPRs)
typedef __attribute__((ext_vector_type(4))) float v4f;   // MFMA accumulator

// bf16 round-to-nearest-even
static __device__ __forceinline__ uint16_t f2bf(float f) {
    uint32_t u = __float_as_uint(f);
    u = (u + 0x7fff + ((u >> 16) & 1)) >> 16;
    return (uint16_t)u;
}
static __device__ __forceinline__ float bf2f(uint16_t h) { return __uint_as_float((uint32_t)h << 16); }
static __device__ __forceinline__ float bf_lo(uint32_t u) { return __uint_as_float(u << 16); }
static __device__ __forceinline__ float bf_hi(uint32_t u) { return __uint_as_float(u & 0xffff0000u); }

// ---------------- count + rank + W-pack (fused, independent work) ----------------
// rank[e] = edge's slot within its target bucket (atomicAdd return) -> fill has NO atomics.

__global__ void countpack_kernel(const int* __restrict__ col, int* __restrict__ cnt,
                                 int* __restrict__ rnk, int E,
                                 const float* __restrict__ W1, const float* __restrict__ W2,
                                 uint16_t* __restrict__ Wh, uint16_t* __restrict__ Wl) {
    int tid = blockIdx.x * blockDim.x + threadIdx.x;
    if (tid < 2 * 16384) {
        int layer = tid >> 14;
        int li = tid & 16383;
        int j = li & 7, lane = (li >> 3) & 63, f = li >> 9;
        int kstep = f >> 3, tile = f & 7;
        int k = kstep * 32 + ((lane >> 4) * 8) + j;
        int nn = tile * 16 + (lane & 15);
        const float* W = layer ? W2 : W1;
        float v = W[k * 128 + nn];
        uint16_t h = f2bf(v);
        Wh[tid] = h;
        Wl[tid] = f2bf(v - bf2f(h));
    }
    if (tid < E) rnk[tid] = atomicAdd(&cnt[col[tid]], 1);
}

// ---------------- scan phase A: per-chunk sums (+ fused dinv + P init) ----------------

__global__ __launch_bounds__(256) void scanA_kernel(const int* __restrict__ cnt,
                                                    int* __restrict__ bsum,
                                                    float* __restrict__ dinv,
                                                    const float* __restrict__ bfc,
                                                    float* __restrict__ P1,
                                                    float* __restrict__ P2, int n) {
    __shared__ int wsum[4];
    int b = blockIdx.x, t = threadIdx.x;
    int base = b * SCAN_CHUNK;
    float4 bb = *(const float4*)bfc;
    int s = 0;
#pragma unroll
    for (int k = 0; k < SCAN_CHUNK / 256; k++) {
        int i = base + k * 256 + t;
        if (i < n) {
            int c = cnt[i];
            s += c;
            dinv[i] = rsqrtf((float)c + 1.0f);
            ((float4*)P1)[i] = bb;                                   // bias init for atomic accum
            ((float4*)P2)[i] = make_float4(0.f, 0.f, 0.f, 0.f);
        }
    }
#pragma unroll
    for (int off = 32; off > 0; off >>= 1) s += __shfl_xor(s, off, 64);
    if ((t & 63) == 0) wsum[t >> 6] = s;
    __syncthreads();
    if (t == 0) bsum[b] = wsum[0] + wsum[1] + wsum[2] + wsum[3];
}

// ---------------- scan phase C: local exclusive scan, block bases inlined ----------------

__global__ __launch_bounds__(256) void scanC_kernel(const int* __restrict__ cnt,
                                                    const int* __restrict__ bsum,
                                                    int* __restrict__ offs, int n, int nb) {
    __shared__ int stage[SCAN_CHUNK];
    __shared__ int res[SCAN_CHUNK];
    __shared__ int tsum[256];
    __shared__ int sb[64];
    int b = blockIdx.x, t = threadIdx.x;
    if (t < 64) {
        int v = (t < nb) ? bsum[t] : 0;
        int inc = v;
#pragma unroll
        for (int off = 1; off < 64; off <<= 1) {
            int u = __shfl_up(inc, off, 64);
            if (t >= off) inc += u;
        }
        sb[t] = inc;
    }
    int base = b * SCAN_CHUNK;
#pragma unroll
    for (int k = 0; k < SCAN_CHUNK / 256; k++) {
        int i = base + k * 256 + t;
        stage[k * 256 + t] = (i < n) ? cnt[i] : 0;
    }
    __syncthreads();
    int my = 0;
#pragma unroll
    for (int j = 0; j < 8; j++) my += stage[t * 8 + j];
    tsum[t] = my;
    __syncthreads();
    for (int off = 1; off < 256; off <<= 1) {
        int v = (t >= off) ? tsum[t - off] : 0;
        __syncthreads();
        tsum[t] += v;
        __syncthreads();
    }
    int bbase = (b == 0) ? 0 : sb[b - 1];
    int run = tsum[t] - my + bbase;
#pragma unroll
    for (int j = 0; j < 8; j++) {
        res[t * 8 + j] = run;
        run += stage[t * 8 + j];
    }
    __syncthreads();
#pragma unroll
    for (int k = 0; k < SCAN_CHUNK / 256; k++) {
        int i = base + k * 256 + t;
        if (i < n) offs[i] = res[k * 256 + t];
    }
    if (b == gridDim.x - 1 && t == 0) offs[n] = sb[nb - 1];
}

// ---------------- MFMA GEMM body (4 waves) ----------------
// split-bf16 (Markidis): A@W ~= Ah@Wh + Ah@Wl + Al@Wh; result pre-scaled by dinv.
// C-write is QUARTER-BLOCKED: Cb[q][gr][32] bf16 (q = feature/32) so the downstream
// gather reads a 3.2 MB table per quarter (fits one XCD's 4 MiB L2).

static __device__ __forceinline__ void gemm_body(const uint16_t Ah[][LDA],
                                                 const uint16_t Al[][LDA],
                                                 const uint16_t* __restrict__ Wph,
                                                 const uint16_t* __restrict__ Wpl,
                                                 const float* __restrict__ dinv,
                                                 uint16_t* __restrict__ Cb,
                                                 int base_row, int M, int t) {
    int lane = t & 63, w = t >> 6;
    int m_l = lane & 15, quad = lane >> 4;
    int arow = w * 16 + m_l;

    v4f acc[8];
#pragma unroll
    for (int i = 0; i < 8; i++) acc[i] = (v4f){0.f, 0.f, 0.f, 0.f};

#pragma unroll
    for (int ks = 0; ks < 4; ks++) {
        v8s ah = *(const v8s*)&Ah[arow][ks * 32 + quad * 8];
        v8s al = *(const v8s*)&Al[arow][ks * 32 + quad * 8];
#pragma unroll
        for (int ti = 0; ti < 8; ti++) {
            int f = ks * 8 + ti;
            v8s bh = *(const v8s*)(Wph + ((size_t)(f * 64 + lane)) * 8);
            v8s bl = *(const v8s*)(Wpl + ((size_t)(f * 64 + lane)) * 8);
            acc[ti] = __builtin_amdgcn_mfma_f32_16x16x32_bf16(al, bh, acc[ti], 0, 0, 0);
            acc[ti] = __builtin_amdgcn_mfma_f32_16x16x32_bf16(ah, bl, acc[ti], 0, 0, 0);
            acc[ti] = __builtin_amdgcn_mfma_f32_16x16x32_bf16(ah, bh, acc[ti], 0, 0, 0);
        }
    }

    int rbase = base_row + w * 16 + quad * 4;
#pragma unroll
    for (int reg = 0; reg < 4; reg++) {
        int gr = rbase + reg;
        if (gr < M) {
            float di = dinv[gr];
#pragma unroll
            for (int ti = 0; ti < 8; ti++) {
                // feature = ti*16 + m_l; quarter = ti>>1; within-quarter = (ti&1)*16 + m_l
                Cb[(((size_t)(ti >> 1)) * M + gr) * 32 + (ti & 1) * 16 + m_l] =
                    f2bf(di * acc[ti][reg]);
            }
        }
    }
}

// ---------------- fused: CSR fill (block-role split) + layer-1 GEMM ----------------

__global__ __launch_bounds__(256) void fillgemm_kernel(const int* __restrict__ row,
                                                       const int* __restrict__ col,
                                                       const int* __restrict__ rnk,
                                                       const int* __restrict__ offs,
                                                       int* __restrict__ adj, int E,
                                                       const float* __restrict__ A,
                                                       const uint16_t* __restrict__ Wph,
                                                       const uint16_t* __restrict__ Wpl,
                                                       const float* __restrict__ dinv,
                                                       uint16_t* __restrict__ Cb, int M,
                                                       int nbG) {
    __shared__ uint16_t Ah[64][LDA];
    __shared__ uint16_t Al[64][LDA];
    int t = threadIdx.x;

    if (blockIdx.x >= nbG) {   // ---- fill role (atomic-free scatter) ----
        int e = (blockIdx.x - nbG) * 256 + t;
        if (e < E) adj[offs[col[e]] + rnk[e]] = row[e];
        return;
    }

    // ---- gemm role: stage x-tile as split bf16, then MFMA ----
    int base_row = blockIdx.x * 64;
#pragma unroll
    for (int kk = 0; kk < 8; kk++) {
        int idx = kk * 256 + t;
        int r = idx >> 5;
        int c4 = idx & 31;
        int gr = base_row + r;
        float4 f = (gr < M) ? *(const float4*)(A + (size_t)gr * D + c4 * 4)
                            : make_float4(0.f, 0.f, 0.f, 0.f);
        uint16_t h0 = f2bf(f.x), h1 = f2bf(f.y), h2 = f2bf(f.z), h3 = f2bf(f.w);
        uint16_t l0 = f2bf(f.x - bf2f(h0)), l1 = f2bf(f.y - bf2f(h1));
        uint16_t l2 = f2bf(f.z - bf2f(h2)), l3 = f2bf(f.w - bf2f(h3));
        *(ushort4*)&Ah[r][c4 * 4] = make_ushort4(h0, h1, h2, h3);
        *(ushort4*)&Al[r][c4 * 4] = make_ushort4(l0, l1, l2, l3);
    }
    __syncthreads();
    gemm_body(Ah, Al, Wph, Wpl, dinv, Cb, base_row, M, t);
}

// ---------------- layer-2 GEMM: reads quarter-blocked f32 h1q ----------------

__global__ __launch_bounds__(256) void gemm2_kernel(const float* __restrict__ h1q,
                                                    const uint16_t* __restrict__ Wph,
                                                    const uint16_t* __restrict__ Wpl,
                                                    const float* __restrict__ dinv,
                                                    uint16_t* __restrict__ Cb, int M) {
    __shared__ uint16_t Ah[64][LDA];
    __shared__ uint16_t Al[64][LDA];
    int t = threadIdx.x;
    int base_row = blockIdx.x * 64;
#pragma unroll
    for (int kk = 0; kk < 8; kk++) {
        int idx = kk * 256 + t;
        int r = idx >> 5;
        int c4 = idx & 31;           // feature block: quarter qq = c4>>3, chunk cc = c4&7
        int gr = base_row + r;
        int qq = c4 >> 3, cc = c4 & 7;
        float4 f = (gr < M) ? ((const float4*)h1q)[((size_t)qq * M + gr) * 8 + cc]
                            : make_float4(0.f, 0.f, 0.f, 0.f);
        uint16_t h0 = f2bf(f.x), h1 = f2bf(f.y), h2 = f2bf(f.z), h3 = f2bf(f.w);
        uint16_t l0 = f2bf(f.x - bf2f(h0)), l1 = f2bf(f.y - bf2f(h1));
        uint16_t l2 = f2bf(f.z - bf2f(h2)), l3 = f2bf(f.w - bf2f(h3));
        *(ushort4*)&Ah[r][c4 * 4] = make_ushort4(h0, h1, h2, h3);
        *(ushort4*)&Al[r][c4 * 4] = make_ushort4(l0, l1, l2, l3);
    }
    __syncthreads();
    gemm_body(Ah, Al, Wph, Wpl, dinv, Cb, base_row, M, t);
}

// ---------------- quartered aggregation, layer 1 (group-per-node, 8-deep MLP) ----------
// blockIdx%8 -> XCD slot; quarter q = (b&7)>>1: each quarter's 3.2 MB table stays in a
// 2-XCD L2 pair. lane = 16*g + c: GROUP g owns node i = wq*4 + g (4 consecutive nodes
// per wave); the 16 c-lanes cover the quarter's 32 features (2 bf16 per lane). Each
// group runs an 8-deep edge unroll on ITS node -> up to 32 cache lines in flight per
// wave (R5's edge-split mapping had only 8 -> latency-bound at 131 us; this is the fix).

__global__ __launch_bounds__(256) void aggq1_kernel(const uint32_t* __restrict__ xwbq,
                                                    const int* __restrict__ adj,
                                                    const int* __restrict__ offs,
                                                    const float* __restrict__ dinv,
                                                    const float* __restrict__ bias,
                                                    float* __restrict__ h1q, int n) {
    int b = blockIdx.x, t = threadIdx.x;
    int q = (b & 7) >> 1;
    int sub = ((b >> 3) << 1) + (b & 1);              // [0, AGG_BLOCKS/4)
    int wv = t >> 6, lane = t & 63;
    int g = lane >> 4, c = lane & 15;
    const uint32_t* tbl = xwbq + (size_t)q * n * 16;
    float2 bv = ((const float2*)bias)[q * 16 + c];
    int wq = sub * 4 + wv;                            // wave id within quarter
    for (int i = wq * 4 + g; i < n; i += AGG_BLOCKS * 4) {
        uint32_t su = tbl[(size_t)i * 16 + c];
        float a0 = bf_lo(su), a1 = bf_hi(su);
        int j = offs[i], en = offs[i + 1];
        for (; j + 7 < en; j += 8) {
            int e0 = adj[j],     e1 = adj[j + 1], e2 = adj[j + 2], e3 = adj[j + 3];
            int e4 = adj[j + 4], e5 = adj[j + 5], e6 = adj[j + 6], e7 = adj[j + 7];
            uint32_t u0 = tbl[(size_t)e0 * 16 + c];
            uint32_t u1 = tbl[(size_t)e1 * 16 + c];
            uint32_t u2 = tbl[(size_t)e2 * 16 + c];
            uint32_t u3 = tbl[(size_t)e3 * 16 + c];
            uint32_t u4 = tbl[(size_t)e4 * 16 + c];
            uint32_t u5 = tbl[(size_t)e5 * 16 + c];
            uint32_t u6 = tbl[(size_t)e6 * 16 + c];
            uint32_t u7 = tbl[(size_t)e7 * 16 + c];
            a0 += bf_lo(u0); a1 += bf_hi(u0);
            a0 += bf_lo(u1); a1 += bf_hi(u1);
            a0 += bf_lo(u2); a1 += bf_hi(u2);
            a0 += bf_lo(u3); a1 += bf_hi(u3);
            a0 += bf_lo(u4); a1 += bf_hi(u4);
            a0 += bf_lo(u5); a1 += bf_hi(u5);
            a0 += bf_lo(u6); a1 += bf_hi(u6);
            a0 += bf_lo(u7); a1 += bf_hi(u7);
        }
        for (; j + 3 < en; j += 4) {
            int e0 = adj[j], e1 = adj[j + 1], e2 = adj[j + 2], e3 = adj[j + 3];
            uint32_t u0 = tbl[(size_t)e0 * 16 + c];
            uint32_t u1 = tbl[(size_t)e1 * 16 + c];
            uint32_t u2 = tbl[(size_t)e2 * 16 + c];
            uint32_t u3 = tbl[(size_t)e3 * 16 + c];
            a0 += bf_lo(u0); a1 += bf_hi(u0);
            a0 += bf_lo(u1); a1 += bf_hi(u1);
            a0 += bf_lo(u2); a1 += bf_hi(u2);
            a0 += bf_lo(u3); a1 += bf_hi(u3);
        }
        for (; j < en; j++) {
            uint32_t u = tbl[(size_t)adj[j] * 16 + c];
            a0 += bf_lo(u); a1 += bf_hi(u);
        }
        float di = dinv[i];
        float o0 = fmaxf(fmaf(di, a0, bv.x), 0.f);
        float o1 = fmaxf(fmaf(di, a1, bv.y), 0.f);
        ((float2*)h1q)[((size_t)q * n + i) * 16 + c] = make_float2(o0, o1);
    }
}

// ---------------- quartered aggregation, layer 2 + classifier partials ----------------
// Same group-per-node gather; classifier partials (this quarter's 32 features) reduced
// over the group's 16 lanes, then 8 atomicAdds into P1/P2 (pre-initialized in scanA).

__global__ __launch_bounds__(256) void aggq2_kernel(const uint32_t* __restrict__ xwbq,
                                                    const int* __restrict__ adj,
                                                    const int* __restrict__ offs,
                                                    const float* __restrict__ dinv,
                                                    const float* __restrict__ bias,
                                                    const float* __restrict__ Wfc,
                                                    float* __restrict__ P1,
                                                    float* __restrict__ P2, int n) {
    int b = blockIdx.x, t = threadIdx.x;
    int q = (b & 7) >> 1;
    int sub = ((b >> 3) << 1) + (b & 1);
    int wv = t >> 6, lane = t & 63;
    int g = lane >> 4, c = lane & 15;
    const uint32_t* tbl = xwbq + (size_t)q * n * 16;
    float2 bv = ((const float2*)bias)[q * 16 + c];
    const float4* W4 = (const float4*)Wfc;          // Wfc is [256][4] row-major
    float4 w1a = W4[q * 32 + 2 * c];
    float4 w1b = W4[q * 32 + 2 * c + 1];
    float4 w2a = W4[128 + q * 32 + 2 * c];
    float4 w2b = W4[129 + q * 32 + 2 * c];
    int wq = sub * 4 + wv;
    for (int i = wq * 4 + g; i < n; i += AGG_BLOCKS * 4) {
        uint32_t su = tbl[(size_t)i * 16 + c];
        float a0 = bf_lo(su), a1 = bf_hi(su);
        int j = offs[i], en = offs[i + 1];
        for (; j + 7 < en; j += 8) {
            int e0 = adj[j],     e1 = adj[j + 1], e2 = adj[j + 2], e3 = adj[j + 3];
            int e4 = adj[j + 4], e5 = adj[j + 5], e6 = adj[j + 6], e7 = adj[j + 7];
            uint32_t u0 = tbl[(size_t)e0 * 16 + c];
            uint32_t u1 = tbl[(size_t)e1 * 16 + c];
            uint32_t u2 = tbl[(size_t)e2 * 16 + c];
            uint32_t u3 = tbl[(size_t)e3 * 16 + c];
            uint32_t u4 = tbl[(size_t)e4 * 16 + c];
            uint32_t u5 = tbl[(size_t)e5 * 16 + c];
            uint32_t u6 = tbl[(size_t)e6 * 16 + c];
            uint32_t u7 = tbl[(size_t)e7 * 16 + c];
            a0 += bf_lo(u0); a1 += bf_hi(u0);
            a0 += bf_lo(u1); a1 += bf_hi(u1);
            a0 += bf_lo(u2); a1 += bf_hi(u2);
            a0 += bf_lo(u3); a1 += bf_hi(u3);
            a0 += bf_lo(u4); a1 += bf_hi(u4);
            a0 += bf_lo(u5); a1 += bf_hi(u5);
            a0 += bf_lo(u6); a1 += bf_hi(u6);
            a0 += bf_lo(u7); a1 += bf_hi(u7);
        }
        for (; j + 3 < en; j += 4) {
            int e0 = adj[j], e1 = adj[j + 1], e2 = adj[j + 2], e3 = adj[j + 3];
            uint32_t u0 = tbl[(size_t)e0 * 16 + c];
            uint32_t u1 = tbl[(size_t)e1 * 16 + c];
            uint32_t u2 = tbl[(size_t)e2 * 16 + c];
            uint32_t u3 = tbl[(size_t)e3 * 16 + c];
            a0 += bf_lo(u0); a1 += bf_hi(u0);
            a0 += bf_lo(u1); a1 += bf_hi(u1);
            a0 += bf_lo(u2); a1 += bf_hi(u2);
            a0 += bf_lo(u3); a1 += bf_hi(u3);
        }
        for (; j < en; j++) {
            uint32_t u = tbl[(size_t)adj[j] * 16 + c];
            a0 += bf_lo(u); a1 += bf_hi(u);
        }
        float di = dinv[i];
        float o0 = fmaxf(fmaf(di, a0, bv.x), 0.f);
        float o1 = fmaxf(fmaf(di, a1, bv.y), 0.f);
        // classifier partials for this quarter's 2 features per lane
        float p0 = fmaf(o0, w1a.x, o1 * w1b.x), p1 = fmaf(o0, w1a.y, o1 * w1b.y);
        float p2 = fmaf(o0, w1a.z, o1 * w1b.z), p3 = fmaf(o0, w1a.w, o1 * w1b.w);
        float q0 = fmaf(o0, w2a.x, o1 * w2b.x), q1 = fmaf(o0, w2a.y, o1 * w2b.y);
        float q2 = fmaf(o0, w2a.z, o1 * w2b.z), q3 = fmaf(o0, w2a.w, o1 * w2b.w);
#pragma unroll
        for (int off = 1; off < 16; off <<= 1) {   // reduce across the group's 16 lanes
            p0 += __shfl_xor(p0, off, 64);
            p1 += __shfl_xor(p1, off, 64);
            p2 += __shfl_xor(p2, off, 64);
            p3 += __shfl_xor(p3, off, 64);
            q0 += __shfl_xor(q0, off, 64);
            q1 += __shfl_xor(q1, off, 64);
            q2 += __shfl_xor(q2, off, 64);
            q3 += __shfl_xor(q3, off, 64);
        }
        if (c == 0) {
            atomicAdd(&P1[(size_t)i * 4 + 0], p0);
            atomicAdd(&P1[(size_t)i * 4 + 1], p1);
            atomicAdd(&P1[(size_t)i * 4 + 2], p2);
            atomicAdd(&P1[(size_t)i * 4 + 3], p3);
            atomicAdd(&P2[(size_t)i * 4 + 0], q0);
            atomicAdd(&P2[(size_t)i * 4 + 1], q1);
            atomicAdd(&P2[(size_t)i * 4 + 2], q2);
            atomicAdd(&P2[(size_t)i * 4 + 3], q3);
        }
    }
}

// ---------------- edge classifier: one THREAD per edge ----------------

__global__ __launch_bounds__(256) void edge2_kernel(const int* __restrict__ row,
                                                    const int* __restrict__ col,
                                                    const float* __restrict__ P1,
                                                    const float* __restrict__ P2,
                                                    float* __restrict__ out, int E) {
    int e = blockIdx.x * blockDim.x + threadIdx.x;
    if (e >= E) return;
    int r = row[e], c = col[e];
    float4 a = ((const float4*)P1)[r];
    float4 b = ((const float4*)P2)[c];
    float sx = a.x + b.x, sy = a.y + b.y, sz = a.z + b.z, sw = a.w + b.w;
    float m = fmaxf(fmaxf(sx, sy), fmaxf(sz, sw));
    float e0 = expf(sx - m), e1 = expf(sy - m), e2 = expf(sz - m), e3 = expf(sw - m);
    float lse = m + logf(e0 + e1 + e2 + e3);
    *(float4*)(out + (size_t)e * 4) = make_float4(sx - lse, sy - lse, sz - lse, sw - lse);
}

// ---------------- launch ----------------

extern "C" void kernel_launch(void* const* d_in, const int* in_sizes, int n_in,
                              void* d_out, int out_size, void* d_ws, size_t ws_size,
                              hipStream_t stream) {
    const float* x   = (const float*)d_in[0];
    const int*   ei  = (const int*)d_in[1];
    const float* W1  = (const float*)d_in[2];
    const float* b1  = (const float*)d_in[3];
    const float* W2  = (const float*)d_in[4];
    const float* b2  = (const float*)d_in[5];
    const float* Wfc = (const float*)d_in[6];
    const float* bfc = (const float*)d_in[7];
    float* out = (float*)d_out;

    int n = in_sizes[0] / D;        // 50000
    int E = in_sizes[1] / 2;        // 600000
    const int* row = ei;            // edge_index[0]
    const int* col = ei + E;        // edge_index[1]

    int nbScan = (n + SCAN_CHUNK - 1) / SCAN_CHUNK;   // 25

    // workspace layout (all segments 16B-aligned)
    uint16_t* xwb  = (uint16_t*)d_ws;                    // [4][n][32] bf16 (layer-1 xW, dinv-prescaled)
    uint16_t* xwb2 = xwb + (size_t)n * D;                // [4][n][32] bf16 (layer-2 xW, dinv-prescaled)
    float*    h1q  = (float*)(xwb2 + (size_t)n * D);     // [4][n][32] f32 (layer-1 output)
    int*      cnt  = (int*)(h1q + (size_t)n * D);        // n
    int*      offs = cnt + n;                            // n+1 (+pad)
    int*      bsum = offs + (n + 4);                     // 64
    int*      adj  = bsum + 64;                          // E
    int*      rnk  = adj + E;                            // E (edge rank within bucket)
    float*    dinv = (float*)(rnk + E);                  // n
    uint16_t* Wph  = (uint16_t*)(dinv + n);              // 2*16384 (layer-major)
    uint16_t* Wpl  = Wph + 2 * 16384;                    // 2*16384
    float*    P1   = (float*)(Wpl + 2 * 16384);          // n*4
    float*    P2   = P1 + (size_t)n * 4;                 // n*4

    int nb_e = (E + 255) / 256;
    int nbG  = (n + 63) / 64;

    // CSR count (+ W pack; rank captured from atomicAdd return)
    hipMemsetAsync(cnt, 0, (size_t)n * sizeof(int), stream);
    countpack_kernel<<<nb_e, 256, 0, stream>>>(col, cnt, rnk, E, W1, W2, Wph, Wpl);
    scanA_kernel<<<nbScan, 256, 0, stream>>>(cnt, bsum, dinv, bfc, P1, P2, n);
    scanC_kernel<<<nbScan, 256, 0, stream>>>(cnt, bsum, offs, n, nbScan);

    // fill (CSR scatter) runs concurrently with layer-1 GEMM in one grid
    fillgemm_kernel<<<nbG + nb_e, 256, 0, stream>>>(row, col, rnk, offs, adj, E,
                                                    x, Wph, Wpl, dinv, xwb, n, nbG);

    // layer-1 aggregation: quartered, XCD-pinned, group-per-node 8-deep gather
    aggq1_kernel<<<AGG_BLOCKS, 256, 0, stream>>>((const uint32_t*)xwb, adj, offs, dinv, b1,
                                                 h1q, n);

    // layer-2 GEMM (reads quarter-blocked h1q, writes quarter-blocked xwb2)
    gemm2_kernel<<<nbG, 256, 0, stream>>>(h1q, Wph + 16384, Wpl + 16384, dinv, xwb2, n);

    // layer-2 aggregation + classifier partials (atomic accumulation into P1/P2)
    aggq2_kernel<<<AGG_BLOCKS, 256, 0, stream>>>((const uint32_t*)xwb2, adj, offs, dinv, b2,
                                                 Wfc, P1, P2, n);

    // edge classifier
    edge2_kernel<<<nb_e, 256, 0, stream>>>(row, col, P1, P2, out, E);
}

// Round 7
// 243.613 us; speedup vs baseline: 1.4268x; 1.0434x over previous
//
#include <hip/hip_runtime.h>
#include <math.h>
#include <stdint.h>

#define D 128          // feature dim (d_in = d_h = 128)
#define SCAN_CHUNK 2048
#define LDA 136        // LDS row stride in shorts (+8 pad: 16-way -> 2-way bank conflict)

typedef __attribute__((ext_vector_type(8))) short v8s;   // 8 bf16 (4 VGPRs)
typedef __attribute__((ext_vector_type(4))) float v4f;   // MFMA accumulator

// bf16 round-to-nearest-even
static __device__ __forceinline__ uint16_t f2bf(float f) {
    uint32_t u = __float_as_uint(f);
    u = (u + 0x7fff + ((u >> 16) & 1)) >> 16;
    return (uint16_t)u;
}
static __device__ __forceinline__ float bf2f(uint16_t h) { return __uint_as_float((uint32_t)h << 16); }
static __device__ __forceinline__ float bf_lo(uint32_t u) { return __uint_as_float(u << 16); }
static __device__ __forceinline__ float bf_hi(uint32_t u) { return __uint_as_float(u & 0xffff0000u); }

// ---------------- count + rank + W-pack (fused, independent work) ----------------
// rank[e] = edge's slot within its target bucket (atomicAdd return) -> fill has NO atomics.

__global__ void countpack_kernel(const int* __restrict__ col, int* __restrict__ cnt,
                                 int* __restrict__ rnk, int E,
                                 const float* __restrict__ W1, const float* __restrict__ W2,
                                 uint16_t* __restrict__ Wh, uint16_t* __restrict__ Wl) {
    int tid = blockIdx.x * blockDim.x + threadIdx.x;
    if (tid < 2 * 16384) {
        int layer = tid >> 14;
        int li = tid & 16383;
        int j = li & 7, lane = (li >> 3) & 63, f = li >> 9;
        int kstep = f >> 3, tile = f & 7;
        int k = kstep * 32 + ((lane >> 4) * 8) + j;
        int nn = tile * 16 + (lane & 15);
        const float* W = layer ? W2 : W1;
        float v = W[k * 128 + nn];
        uint16_t h = f2bf(v);
        Wh[tid] = h;
        Wl[tid] = f2bf(v - bf2f(h));
    }
    if (tid < E) rnk[tid] = atomicAdd(&cnt[col[tid]], 1);
}

// ---------------- scan phase A: per-chunk sums (+ fused dinv) ----------------
// Multi-block, coalesced. (Single-block variant measured 134 us @0.17% occupancy — do not revisit.)

__global__ __launch_bounds__(256) void scanA_kernel(const int* __restrict__ cnt,
                                                    int* __restrict__ bsum,
                                                    float* __restrict__ dinv, int n) {
    __shared__ int wsum[4];
    int b = blockIdx.x, t = threadIdx.x;
    int base = b * SCAN_CHUNK;
    int s = 0;
#pragma unroll
    for (int k = 0; k < SCAN_CHUNK / 256; k++) {
        int i = base + k * 256 + t;
        if (i < n) {
            int c = cnt[i];
            s += c;
            dinv[i] = rsqrtf((float)c + 1.0f);
        }
    }
#pragma unroll
    for (int off = 32; off > 0; off >>= 1) s += __shfl_xor(s, off, 64);
    if ((t & 63) == 0) wsum[t >> 6] = s;
    __syncthreads();
    if (t == 0) bsum[b] = wsum[0] + wsum[1] + wsum[2] + wsum[3];
}

// ---------------- scan phase C: local exclusive scan, block bases inlined ----------------

__global__ __launch_bounds__(256) void scanC_kernel(const int* __restrict__ cnt,
                                                    const int* __restrict__ bsum,
                                                    int* __restrict__ offs, int n, int nb) {
    __shared__ int stage[SCAN_CHUNK];
    __shared__ int res[SCAN_CHUNK];
    __shared__ int tsum[256];
    __shared__ int sb[64];
    int b = blockIdx.x, t = threadIdx.x;
    if (t < 64) {
        int v = (t < nb) ? bsum[t] : 0;
        int inc = v;
#pragma unroll
        for (int off = 1; off < 64; off <<= 1) {
            int u = __shfl_up(inc, off, 64);
            if (t >= off) inc += u;
        }
        sb[t] = inc;
    }
    int base = b * SCAN_CHUNK;
#pragma unroll
    for (int k = 0; k < SCAN_CHUNK / 256; k++) {
        int i = base + k * 256 + t;
        stage[k * 256 + t] = (i < n) ? cnt[i] : 0;
    }
    __syncthreads();
    int my = 0;
#pragma unroll
    for (int j = 0; j < 8; j++) my += stage[t * 8 + j];
    tsum[t] = my;
    __syncthreads();
    for (int off = 1; off < 256; off <<= 1) {
        int v = (t >= off) ? tsum[t - off] : 0;
        __syncthreads();
        tsum[t] += v;
        __syncthreads();
    }
    int bbase = (b == 0) ? 0 : sb[b - 1];
    int run = tsum[t] - my + bbase;
#pragma unroll
    for (int j = 0; j < 8; j++) {
        res[t * 8 + j] = run;
        run += stage[t * 8 + j];
    }
    __syncthreads();
#pragma unroll
    for (int k = 0; k < SCAN_CHUNK / 256; k++) {
        int i = base + k * 256 + t;
        if (i < n) offs[i] = res[k * 256 + t];
    }
    if (b == gridDim.x - 1 && t == 0) offs[n] = sb[nb - 1];
}

// ---------------- MFMA GEMM body (4 waves, flat [M][128] bf16 C-write) ----------------
// split-bf16 (Markidis): A@W ~= Ah@Wh + Ah@Wl + Al@Wh; result pre-scaled by dinv.

static __device__ __forceinline__ void gemm_body(const uint16_t Ah[][LDA],
                                                 const uint16_t Al[][LDA],
                                                 const uint16_t* __restrict__ Wph,
                                                 const uint16_t* __restrict__ Wpl,
                                                 const float* __restrict__ dinv,
                                                 uint16_t* __restrict__ Cb,
                                                 int base_row, int M, int t) {
    int lane = t & 63, w = t >> 6;
    int m_l = lane & 15, quad = lane >> 4;
    int arow = w * 16 + m_l;

    v4f acc[8];
#pragma unroll
    for (int i = 0; i < 8; i++) acc[i] = (v4f){0.f, 0.f, 0.f, 0.f};

#pragma unroll
    for (int ks = 0; ks < 4; ks++) {
        v8s ah = *(const v8s*)&Ah[arow][ks * 32 + quad * 8];
        v8s al = *(const v8s*)&Al[arow][ks * 32 + quad * 8];
#pragma unroll
        for (int ti = 0; ti < 8; ti++) {
            int f = ks * 8 + ti;
            v8s bh = *(const v8s*)(Wph + ((size_t)(f * 64 + lane)) * 8);
            v8s bl = *(const v8s*)(Wpl + ((size_t)(f * 64 + lane)) * 8);
            acc[ti] = __builtin_amdgcn_mfma_f32_16x16x32_bf16(al, bh, acc[ti], 0, 0, 0);
            acc[ti] = __builtin_amdgcn_mfma_f32_16x16x32_bf16(ah, bl, acc[ti], 0, 0, 0);
            acc[ti] = __builtin_amdgcn_mfma_f32_16x16x32_bf16(ah, bh, acc[ti], 0, 0, 0);
        }
    }

    int rbase = base_row + w * 16 + quad * 4;
#pragma unroll
    for (int reg = 0; reg < 4; reg++) {
        int gr = rbase + reg;
        if (gr < M) {
            float di = dinv[gr];
#pragma unroll
            for (int ti = 0; ti < 8; ti++) {
                Cb[(size_t)gr * D + ti * 16 + m_l] = f2bf(di * acc[ti][reg]);
            }
        }
    }
}

// f32 [M][128] row-major A-tile -> split-bf16 LDS staging (shared by both GEMMs)
static __device__ __forceinline__ void stage_tile(uint16_t Ah[][LDA], uint16_t Al[][LDA],
                                                  const float* __restrict__ A,
                                                  int base_row, int M, int t) {
#pragma unroll
    for (int kk = 0; kk < 8; kk++) {
        int idx = kk * 256 + t;
        int r = idx >> 5;
        int c4 = idx & 31;
        int gr = base_row + r;
        float4 f = (gr < M) ? *(const float4*)(A + (size_t)gr * D + c4 * 4)
                            : make_float4(0.f, 0.f, 0.f, 0.f);
        uint16_t h0 = f2bf(f.x), h1 = f2bf(f.y), h2 = f2bf(f.z), h3 = f2bf(f.w);
        uint16_t l0 = f2bf(f.x - bf2f(h0)), l1 = f2bf(f.y - bf2f(h1));
        uint16_t l2 = f2bf(f.z - bf2f(h2)), l3 = f2bf(f.w - bf2f(h3));
        *(ushort4*)&Ah[r][c4 * 4] = make_ushort4(h0, h1, h2, h3);
        *(ushort4*)&Al[r][c4 * 4] = make_ushort4(l0, l1, l2, l3);
    }
}

// ---------------- fused: CSR fill (block-role split) + layer-1 GEMM ----------------

__global__ __launch_bounds__(256) void fillgemm_kernel(const int* __restrict__ row,
                                                       const int* __restrict__ col,
                                                       const int* __restrict__ rnk,
                                                       const int* __restrict__ offs,
                                                       int* __restrict__ adj, int E,
                                                       const float* __restrict__ A,
                                                       const uint16_t* __restrict__ Wph,
                                                       const uint16_t* __restrict__ Wpl,
                                                       const float* __restrict__ dinv,
                                                       uint16_t* __restrict__ Cb, int M,
                                                       int nbG) {
    __shared__ uint16_t Ah[64][LDA];
    __shared__ uint16_t Al[64][LDA];
    int t = threadIdx.x;

    if (blockIdx.x >= nbG) {   // ---- fill role (atomic-free scatter) ----
        int e = (blockIdx.x - nbG) * 256 + t;
        if (e < E) adj[offs[col[e]] + rnk[e]] = row[e];
        return;
    }

    int base_row = blockIdx.x * 64;
    stage_tile(Ah, Al, A, base_row, M, t);
    __syncthreads();
    gemm_body(Ah, Al, Wph, Wpl, dinv, Cb, base_row, M, t);
}

// ---------------- plain GEMM (layer 2: h -> xwb2) ----------------

__global__ __launch_bounds__(256) void gemm_kernel(const float* __restrict__ A,
                                                   const uint16_t* __restrict__ Wph,
                                                   const uint16_t* __restrict__ Wpl,
                                                   const float* __restrict__ dinv,
                                                   uint16_t* __restrict__ Cb, int M) {
    __shared__ uint16_t Ah[64][LDA];
    __shared__ uint16_t Al[64][LDA];
    int t = threadIdx.x;
    int base_row = blockIdx.x * 64;
    stage_tile(Ah, Al, A, base_row, M, t);
    __syncthreads();
    gemm_body(Ah, Al, Wph, Wpl, dinv, Cb, base_row, M, t);
}

// ---------------- aggregation, layer 1: one wave per node, DOUBLE-ROW gather ----------
// lane = 32*half + c. Each half processes interleaved halves of the edge list with an
// 8-deep unroll; each wave-load touches TWO 256 B rows (uint2 = 8 B/lane) -> 64 lines
// in flight per wave (2x the single-row version) at half the load-instruction count.
// Cross-half combine: 4x shfl_xor(32). Half 0 writes the 512 B f32 output row.

__global__ __launch_bounds__(256) void agg1_kernel(const uint2* __restrict__ tb2,
                                                   const int* __restrict__ adj,
                                                   const int* __restrict__ offs,
                                                   const float* __restrict__ dinv,
                                                   const float* __restrict__ bias,
                                                   float* __restrict__ hout, int n) {
    int wave = (int)((blockIdx.x * (size_t)blockDim.x + threadIdx.x) >> 6);
    if (wave >= n) return;
    int lane = threadIdx.x & 63;
    int half = lane >> 5, c = lane & 31;
    int i = wave;
    float a0 = 0.f, a1 = 0.f, a2 = 0.f, a3 = 0.f;
    if (half == 0) {   // self-loop contribution (once)
        uint2 su = tb2[(size_t)i * 32 + c];
        a0 = bf_lo(su.x); a1 = bf_hi(su.x);
        a2 = bf_lo(su.y); a3 = bf_hi(su.y);
    }
    int s = offs[i];
    int deg = offs[i + 1] - s;
    int cnt_h = (deg + 1 - half) >> 1;   // edges handled by this half
    int base = s + half;                  // this half's edges: base, base+2, base+4, ...
    int k = 0;
    for (; k + 8 <= cnt_h; k += 8) {
        int e0 = adj[base + 2 * k];
        int e1 = adj[base + 2 * k + 2];
        int e2 = adj[base + 2 * k + 4];
        int e3 = adj[base + 2 * k + 6];
        int e4 = adj[base + 2 * k + 8];
        int e5 = adj[base + 2 * k + 10];
        int e6 = adj[base + 2 * k + 12];
        int e7 = adj[base + 2 * k + 14];
        uint2 u0 = tb2[(size_t)e0 * 32 + c];
        uint2 u1 = tb2[(size_t)e1 * 32 + c];
        uint2 u2 = tb2[(size_t)e2 * 32 + c];
        uint2 u3 = tb2[(size_t)e3 * 32 + c];
        uint2 u4 = tb2[(size_t)e4 * 32 + c];
        uint2 u5 = tb2[(size_t)e5 * 32 + c];
        uint2 u6 = tb2[(size_t)e6 * 32 + c];
        uint2 u7 = tb2[(size_t)e7 * 32 + c];
        a0 += bf_lo(u0.x); a1 += bf_hi(u0.x); a2 += bf_lo(u0.y); a3 += bf_hi(u0.y);
        a0 += bf_lo(u1.x); a1 += bf_hi(u1.x); a2 += bf_lo(u1.y); a3 += bf_hi(u1.y);
        a0 += bf_lo(u2.x); a1 += bf_hi(u2.x); a2 += bf_lo(u2.y); a3 += bf_hi(u2.y);
        a0 += bf_lo(u3.x); a1 += bf_hi(u3.x); a2 += bf_lo(u3.y); a3 += bf_hi(u3.y);
        a0 += bf_lo(u4.x); a1 += bf_hi(u4.x); a2 += bf_lo(u4.y); a3 += bf_hi(u4.y);
        a0 += bf_lo(u5.x); a1 += bf_hi(u5.x); a2 += bf_lo(u5.y); a3 += bf_hi(u5.y);
        a0 += bf_lo(u6.x); a1 += bf_hi(u6.x); a2 += bf_lo(u6.y); a3 += bf_hi(u6.y);
        a0 += bf_lo(u7.x); a1 += bf_hi(u7.x); a2 += bf_lo(u7.y); a3 += bf_hi(u7.y);
    }
    for (; k + 4 <= cnt_h; k += 4) {
        int e0 = adj[base + 2 * k];
        int e1 = adj[base + 2 * k + 2];
        int e2 = adj[base + 2 * k + 4];
        int e3 = adj[base + 2 * k + 6];
        uint2 u0 = tb2[(size_t)e0 * 32 + c];
        uint2 u1 = tb2[(size_t)e1 * 32 + c];
        uint2 u2 = tb2[(size_t)e2 * 32 + c];
        uint2 u3 = tb2[(size_t)e3 * 32 + c];
        a0 += bf_lo(u0.x); a1 += bf_hi(u0.x); a2 += bf_lo(u0.y); a3 += bf_hi(u0.y);
        a0 += bf_lo(u1.x); a1 += bf_hi(u1.x); a2 += bf_lo(u1.y); a3 += bf_hi(u1.y);
        a0 += bf_lo(u2.x); a1 += bf_hi(u2.x); a2 += bf_lo(u2.y); a3 += bf_hi(u2.y);
        a0 += bf_lo(u3.x); a1 += bf_hi(u3.x); a2 += bf_lo(u3.y); a3 += bf_hi(u3.y);
    }
    for (; k < cnt_h; k++) {
        int e0 = adj[base + 2 * k];
        uint2 u0 = tb2[(size_t)e0 * 32 + c];
        a0 += bf_lo(u0.x); a1 += bf_hi(u0.x); a2 += bf_lo(u0.y); a3 += bf_hi(u0.y);
    }
    a0 += __shfl_xor(a0, 32, 64);
    a1 += __shfl_xor(a1, 32, 64);
    a2 += __shfl_xor(a2, 32, 64);
    a3 += __shfl_xor(a3, 32, 64);
    float di = dinv[i];
    float4 bv = ((const float4*)bias)[c];
    float o0 = fmaxf(fmaf(di, a0, bv.x), 0.f);
    float o1 = fmaxf(fmaf(di, a1, bv.y), 0.f);
    float o2 = fmaxf(fmaf(di, a2, bv.z), 0.f);
    float o3 = fmaxf(fmaf(di, a3, bv.w), 0.f);
    if (half == 0)
        ((float4*)(hout + (size_t)i * D))[c] = make_float4(o0, o1, o2, o3);
}

// ---------------- layer-2 aggregation + classifier precompute, DOUBLE-ROW gather ------
// Same gather; lane owns features 4c..4c+3, so each half's 32 lanes cover all 128
// features -> the classifier dot is a 32-wide butterfly (both halves independently
// compute the full sum; lane 0 writes).

__global__ __launch_bounds__(256) void agg2pq_kernel(const uint2* __restrict__ tb2,
                                                     const int* __restrict__ adj,
                                                     const int* __restrict__ offs,
                                                     const float* __restrict__ dinv,
                                                     const float* __restrict__ bias,
                                                     const float* __restrict__ Wfc,
                                                     const float* __restrict__ bfc,
                                                     float* __restrict__ P1,
                                                     float* __restrict__ P2, int n) {
    int wave = (int)((blockIdx.x * (size_t)blockDim.x + threadIdx.x) >> 6);
    if (wave >= n) return;
    int lane = threadIdx.x & 63;
    int half = lane >> 5, c = lane & 31;
    int i = wave;
    float a0 = 0.f, a1 = 0.f, a2 = 0.f, a3 = 0.f;
    if (half == 0) {
        uint2 su = tb2[(size_t)i * 32 + c];
        a0 = bf_lo(su.x); a1 = bf_hi(su.x);
        a2 = bf_lo(su.y); a3 = bf_hi(su.y);
    }
    int s = offs[i];
    int deg = offs[i + 1] - s;
    int cnt_h = (deg + 1 - half) >> 1;
    int base = s + half;
    int k = 0;
    for (; k + 8 <= cnt_h; k += 8) {
        int e0 = adj[base + 2 * k];
        int e1 = adj[base + 2 * k + 2];
        int e2 = adj[base + 2 * k + 4];
        int e3 = adj[base + 2 * k + 6];
        int e4 = adj[base + 2 * k + 8];
        int e5 = adj[base + 2 * k + 10];
        int e6 = adj[base + 2 * k + 12];
        int e7 = adj[base + 2 * k + 14];
        uint2 u0 = tb2[(size_t)e0 * 32 + c];
        uint2 u1 = tb2[(size_t)e1 * 32 + c];
        uint2 u2 = tb2[(size_t)e2 * 32 + c];
        uint2 u3 = tb2[(size_t)e3 * 32 + c];
        uint2 u4 = tb2[(size_t)e4 * 32 + c];
        uint2 u5 = tb2[(size_t)e5 * 32 + c];
        uint2 u6 = tb2[(size_t)e6 * 32 + c];
        uint2 u7 = tb2[(size_t)e7 * 32 + c];
        a0 += bf_lo(u0.x); a1 += bf_hi(u0.x); a2 += bf_lo(u0.y); a3 += bf_hi(u0.y);
        a0 += bf_lo(u1.x); a1 += bf_hi(u1.x); a2 += bf_lo(u1.y); a3 += bf_hi(u1.y);
        a0 += bf_lo(u2.x); a1 += bf_hi(u2.x); a2 += bf_lo(u2.y); a3 += bf_hi(u2.y);
        a0 += bf_lo(u3.x); a1 += bf_hi(u3.x); a2 += bf_lo(u3.y); a3 += bf_hi(u3.y);
        a0 += bf_lo(u4.x); a1 += bf_hi(u4.x); a2 += bf_lo(u4.y); a3 += bf_hi(u4.y);
        a0 += bf_lo(u5.x); a1 += bf_hi(u5.x); a2 += bf_lo(u5.y); a3 += bf_hi(u5.y);
        a0 += bf_lo(u6.x); a1 += bf_hi(u6.x); a2 += bf_lo(u6.y); a3 += bf_hi(u6.y);
        a0 += bf_lo(u7.x); a1 += bf_hi(u7.x); a2 += bf_lo(u7.y); a3 += bf_hi(u7.y);
    }
    for (; k + 4 <= cnt_h; k += 4) {
        int e0 = adj[base + 2 * k];
        int e1 = adj[base + 2 * k + 2];
        int e2 = adj[base + 2 * k + 4];
        int e3 = adj[base + 2 * k + 6];
        uint2 u0 = tb2[(size_t)e0 * 32 + c];
        uint2 u1 = tb2[(size_t)e1 * 32 + c];
        uint2 u2 = tb2[(size_t)e2 * 32 + c];
        uint2 u3 = tb2[(size_t)e3 * 32 + c];
        a0 += bf_lo(u0.x); a1 += bf_hi(u0.x); a2 += bf_lo(u0.y); a3 += bf_hi(u0.y);
        a0 += bf_lo(u1.x); a1 += bf_hi(u1.x); a2 += bf_lo(u1.y); a3 += bf_hi(u1.y);
        a0 += bf_lo(u2.x); a1 += bf_hi(u2.x); a2 += bf_lo(u2.y); a3 += bf_hi(u2.y);
        a0 += bf_lo(u3.x); a1 += bf_hi(u3.x); a2 += bf_lo(u3.y); a3 += bf_hi(u3.y);
    }
    for (; k < cnt_h; k++) {
        int e0 = adj[base + 2 * k];
        uint2 u0 = tb2[(size_t)e0 * 32 + c];
        a0 += bf_lo(u0.x); a1 += bf_hi(u0.x); a2 += bf_lo(u0.y); a3 += bf_hi(u0.y);
    }
    a0 += __shfl_xor(a0, 32, 64);
    a1 += __shfl_xor(a1, 32, 64);
    a2 += __shfl_xor(a2, 32, 64);
    a3 += __shfl_xor(a3, 32, 64);
    float di = dinv[i];
    float4 bv = ((const float4*)bias)[c];
    float o0 = fmaxf(fmaf(di, a0, bv.x), 0.f);
    float o1 = fmaxf(fmaf(di, a1, bv.y), 0.f);
    float o2 = fmaxf(fmaf(di, a2, bv.z), 0.f);
    float o3 = fmaxf(fmaf(di, a3, bv.w), 0.f);

    // classifier partials: lane covers features 4c..4c+3
    const float4* W4 = (const float4*)Wfc;          // Wfc is [256][4] row-major
    float4 wr0 = W4[4 * c + 0], wr1 = W4[4 * c + 1];
    float4 wr2 = W4[4 * c + 2], wr3 = W4[4 * c + 3];
    float4 vr0 = W4[128 + 4 * c + 0], vr1 = W4[128 + 4 * c + 1];
    float4 vr2 = W4[128 + 4 * c + 2], vr3 = W4[128 + 4 * c + 3];
    float p0 = fmaf(o0, wr0.x, fmaf(o1, wr1.x, fmaf(o2, wr2.x, o3 * wr3.x)));
    float p1 = fmaf(o0, wr0.y, fmaf(o1, wr1.y, fmaf(o2, wr2.y, o3 * wr3.y)));
    float p2 = fmaf(o0, wr0.z, fmaf(o1, wr1.z, fmaf(o2, wr2.z, o3 * wr3.z)));
    float p3 = fmaf(o0, wr0.w, fmaf(o1, wr1.w, fmaf(o2, wr2.w, o3 * wr3.w)));
    float q0 = fmaf(o0, vr0.x, fmaf(o1, vr1.x, fmaf(o2, vr2.x, o3 * vr3.x)));
    float q1 = fmaf(o0, vr0.y, fmaf(o1, vr1.y, fmaf(o2, vr2.y, o3 * vr3.y)));
    float q2 = fmaf(o0, vr0.z, fmaf(o1, vr1.z, fmaf(o2, vr2.z, o3 * vr3.z)));
    float q3 = fmaf(o0, vr0.w, fmaf(o1, vr1.w, fmaf(o2, vr2.w, o3 * vr3.w)));
#pragma unroll
    for (int off = 1; off < 32; off <<= 1) {   // 32-wide: each half covers all features
        p0 += __shfl_xor(p0, off, 64);
        p1 += __shfl_xor(p1, off, 64);
        p2 += __shfl_xor(p2, off, 64);
        p3 += __shfl_xor(p3, off, 64);
        q0 += __shfl_xor(q0, off, 64);
        q1 += __shfl_xor(q1, off, 64);
        q2 += __shfl_xor(q2, off, 64);
        q3 += __shfl_xor(q3, off, 64);
    }
    if (lane == 0) {
        float4 bb = *(const float4*)bfc;
        *(float4*)(P1 + (size_t)i * 4) = make_float4(p0 + bb.x, p1 + bb.y, p2 + bb.z, p3 + bb.w);
        *(float4*)(P2 + (size_t)i * 4) = make_float4(q0, q1, q2, q3);
    }
}

// ---------------- edge classifier: one THREAD per edge ----------------

__global__ __launch_bounds__(256) void edge2_kernel(const int* __restrict__ row,
                                                    const int* __restrict__ col,
                                                    const float* __restrict__ P1,
                                                    const float* __restrict__ P2,
                                                    float* __restrict__ out, int E) {
    int e = blockIdx.x * blockDim.x + threadIdx.x;
    if (e >= E) return;
    int r = row[e], c = col[e];
    float4 a = ((const float4*)P1)[r];
    float4 b = ((const float4*)P2)[c];
    float sx = a.x + b.x, sy = a.y + b.y, sz = a.z + b.z, sw = a.w + b.w;
    float m = fmaxf(fmaxf(sx, sy), fmaxf(sz, sw));
    float e0 = expf(sx - m), e1 = expf(sy - m), e2 = expf(sz - m), e3 = expf(sw - m);
    float lse = m + logf(e0 + e1 + e2 + e3);
    *(float4*)(out + (size_t)e * 4) = make_float4(sx - lse, sy - lse, sz - lse, sw - lse);
}

// ---------------- launch ----------------

extern "C" void kernel_launch(void* const* d_in, const int* in_sizes, int n_in,
                              void* d_out, int out_size, void* d_ws, size_t ws_size,
                              hipStream_t stream) {
    const float* x   = (const float*)d_in[0];
    const int*   ei  = (const int*)d_in[1];
    const float* W1  = (const float*)d_in[2];
    const float* b1  = (const float*)d_in[3];
    const float* W2  = (const float*)d_in[4];
    const float* b2  = (const float*)d_in[5];
    const float* Wfc = (const float*)d_in[6];
    const float* bfc = (const float*)d_in[7];
    float* out = (float*)d_out;

    int n = in_sizes[0] / D;        // 50000
    int E = in_sizes[1] / 2;        // 600000
    const int* row = ei;            // edge_index[0]
    const int* col = ei + E;        // edge_index[1]

    int nbScan = (n + SCAN_CHUNK - 1) / SCAN_CHUNK;   // 25

    // workspace layout (all segments 16B-aligned)
    uint16_t* xwb  = (uint16_t*)d_ws;                    // [n][128] bf16 (layer-1 xW, dinv-prescaled)
    uint16_t* xwb2 = xwb + (size_t)n * D;                // [n][128] bf16 (layer-2 xW, dinv-prescaled)
    float*    h    = (float*)(xwb2 + (size_t)n * D);     // [n][128] f32 (layer-1 output)
    int*      cnt  = (int*)(h + (size_t)n * D);          // n
    int*      offs = cnt + n;                            // n+1 (+pad)
    int*      bsum = offs + (n + 4);                     // 64
    int*      adj  = bsum + 64;                          // E
    int*      rnk  = adj + E;                            // E (edge rank within bucket)
    float*    dinv = (float*)(rnk + E);                  // n
    uint16_t* Wph  = (uint16_t*)(dinv + n);              // 2*16384 (layer-major)
    uint16_t* Wpl  = Wph + 2 * 16384;                    // 2*16384
    float*    P1   = (float*)(Wpl + 2 * 16384);          // n*4
    float*    P2   = P1 + (size_t)n * 4;                 // n*4

    int nb_e = (E + 255) / 256;
    int nbG  = (n + 63) / 64;
    int nbA  = (n + 3) / 4;

    // CSR count (+ W pack; rank captured from atomicAdd return)
    hipMemsetAsync(cnt, 0, (size_t)n * sizeof(int), stream);
    countpack_kernel<<<nb_e, 256, 0, stream>>>(col, cnt, rnk, E, W1, W2, Wph, Wpl);
    scanA_kernel<<<nbScan, 256, 0, stream>>>(cnt, bsum, dinv, n);
    scanC_kernel<<<nbScan, 256, 0, stream>>>(cnt, bsum, offs, n, nbScan);

    // fill (CSR scatter) runs concurrently with layer-1 GEMM in one grid
    fillgemm_kernel<<<nbG + nb_e, 256, 0, stream>>>(row, col, rnk, offs, adj, E,
                                                    x, Wph, Wpl, dinv, xwb, n, nbG);

    // layer-1 aggregation (double-row gather) -> h f32
    agg1_kernel<<<nbA, 256, 0, stream>>>((const uint2*)xwb, adj, offs, dinv, b1, h, n);

    // layer-2 GEMM
    gemm_kernel<<<nbG, 256, 0, stream>>>(h, Wph + 16384, Wpl + 16384, dinv, xwb2, n);

    // layer-2 aggregation + classifier precompute (double-row gather)
    agg2pq_kernel<<<nbA, 256, 0, stream>>>((const uint2*)xwb2, adj, offs, dinv, b2,
                                           Wfc, bfc, P1, P2, n);

    // edge classifier
    edge2_kernel<<<nb_e, 256, 0, stream>>>(row, col, P1, P2, out, E);
}

// Round 8
// 232.517 us; speedup vs baseline: 1.4949x; 1.0477x over previous
//
#include <hip/hip_runtime.h>
#include <math.h>
#include <stdint.h>

#define D 128          // feature dim (d_in = d_h = 128)
#define SCAN_CHUNK 2048
#define LDA 136        // LDS row stride in shorts (+8 pad: 16-way -> 2-way bank conflict)

typedef __attribute__((ext_vector_type(8))) short v8s;   // 8 bf16 (4 VGPRs)
typedef __attribute__((ext_vector_type(4))) float v4f;   // MFMA accumulator

// bf16 round-to-nearest-even
static __device__ __forceinline__ uint16_t f2bf(float f) {
    uint32_t u = __float_as_uint(f);
    u = (u + 0x7fff + ((u >> 16) & 1)) >> 16;
    return (uint16_t)u;
}
static __device__ __forceinline__ float bf2f(uint16_t h) { return __uint_as_float((uint32_t)h << 16); }
static __device__ __forceinline__ float bf_lo(uint32_t u) { return __uint_as_float(u << 16); }
static __device__ __forceinline__ float bf_hi(uint32_t u) { return __uint_as_float(u & 0xffff0000u); }

// ---------------- count + rank + W-pack (fused, independent work) ----------------
// rank[e] = edge's slot within its target bucket (atomicAdd return) -> fill has NO atomics.

__global__ void countpack_kernel(const int* __restrict__ col, int* __restrict__ cnt,
                                 int* __restrict__ rnk, int E,
                                 const float* __restrict__ W1, const float* __restrict__ W2,
                                 uint16_t* __restrict__ Wh, uint16_t* __restrict__ Wl) {
    int tid = blockIdx.x * blockDim.x + threadIdx.x;
    if (tid < 2 * 16384) {
        int layer = tid >> 14;
        int li = tid & 16383;
        int j = li & 7, lane = (li >> 3) & 63, f = li >> 9;
        int kstep = f >> 3, tile = f & 7;
        int k = kstep * 32 + ((lane >> 4) * 8) + j;
        int nn = tile * 16 + (lane & 15);
        const float* W = layer ? W2 : W1;
        float v = W[k * 128 + nn];
        uint16_t h = f2bf(v);
        Wh[tid] = h;
        Wl[tid] = f2bf(v - bf2f(h));
    }
    if (tid < E) rnk[tid] = atomicAdd(&cnt[col[tid]], 1);
}

// ---------------- scan phase A: per-chunk sums (+ fused dinv) ----------------
// Multi-block, coalesced. (Single-block variant measured 134 us @0.17% occupancy — do not revisit.)

__global__ __launch_bounds__(256) void scanA_kernel(const int* __restrict__ cnt,
                                                    int* __restrict__ bsum,
                                                    float* __restrict__ dinv, int n) {
    __shared__ int wsum[4];
    int b = blockIdx.x, t = threadIdx.x;
    int base = b * SCAN_CHUNK;
    int s = 0;
#pragma unroll
    for (int k = 0; k < SCAN_CHUNK / 256; k++) {
        int i = base + k * 256 + t;
        if (i < n) {
            int c = cnt[i];
            s += c;
            dinv[i] = rsqrtf((float)c + 1.0f);
        }
    }
#pragma unroll
    for (int off = 32; off > 0; off >>= 1) s += __shfl_xor(s, off, 64);
    if ((t & 63) == 0) wsum[t >> 6] = s;
    __syncthreads();
    if (t == 0) bsum[b] = wsum[0] + wsum[1] + wsum[2] + wsum[3];
}

// ---------------- scan phase C: local exclusive scan, block bases inlined ----------------

__global__ __launch_bounds__(256) void scanC_kernel(const int* __restrict__ cnt,
                                                    const int* __restrict__ bsum,
                                                    int* __restrict__ offs, int n, int nb) {
    __shared__ int stage[SCAN_CHUNK];
    __shared__ int res[SCAN_CHUNK];
    __shared__ int tsum[256];
    __shared__ int sb[64];
    int b = blockIdx.x, t = threadIdx.x;
    if (t < 64) {
        int v = (t < nb) ? bsum[t] : 0;
        int inc = v;
#pragma unroll
        for (int off = 1; off < 64; off <<= 1) {
            int u = __shfl_up(inc, off, 64);
            if (t >= off) inc += u;
        }
        sb[t] = inc;
    }
    int base = b * SCAN_CHUNK;
#pragma unroll
    for (int k = 0; k < SCAN_CHUNK / 256; k++) {
        int i = base + k * 256 + t;
        stage[k * 256 + t] = (i < n) ? cnt[i] : 0;
    }
    __syncthreads();
    int my = 0;
#pragma unroll
    for (int j = 0; j < 8; j++) my += stage[t * 8 + j];
    tsum[t] = my;
    __syncthreads();
    for (int off = 1; off < 256; off <<= 1) {
        int v = (t >= off) ? tsum[t - off] : 0;
        __syncthreads();
        tsum[t] += v;
        __syncthreads();
    }
    int bbase = (b == 0) ? 0 : sb[b - 1];
    int run = tsum[t] - my + bbase;
#pragma unroll
    for (int j = 0; j < 8; j++) {
        res[t * 8 + j] = run;
        run += stage[t * 8 + j];
    }
    __syncthreads();
#pragma unroll
    for (int k = 0; k < SCAN_CHUNK / 256; k++) {
        int i = base + k * 256 + t;
        if (i < n) offs[i] = res[k * 256 + t];
    }
    if (b == gridDim.x - 1 && t == 0) offs[n] = sb[nb - 1];
}

// ---------------- MFMA GEMM body (4 waves, flat [M][128] bf16 C-write) ----------------
// split-bf16 (Markidis): A@W ~= Ah@Wh + Ah@Wl + Al@Wh; result pre-scaled by dinv.

static __device__ __forceinline__ void gemm_body(const uint16_t Ah[][LDA],
                                                 const uint16_t Al[][LDA],
                                                 const uint16_t* __restrict__ Wph,
                                                 const uint16_t* __restrict__ Wpl,
                                                 const float* __restrict__ dinv,
                                                 uint16_t* __restrict__ Cb,
                                                 int base_row, int M, int t) {
    int lane = t & 63, w = t >> 6;
    int m_l = lane & 15, quad = lane >> 4;
    int arow = w * 16 + m_l;

    v4f acc[8];
#pragma unroll
    for (int i = 0; i < 8; i++) acc[i] = (v4f){0.f, 0.f, 0.f, 0.f};

#pragma unroll
    for (int ks = 0; ks < 4; ks++) {
        v8s ah = *(const v8s*)&Ah[arow][ks * 32 + quad * 8];
        v8s al = *(const v8s*)&Al[arow][ks * 32 + quad * 8];
#pragma unroll
        for (int ti = 0; ti < 8; ti++) {
            int f = ks * 8 + ti;
            v8s bh = *(const v8s*)(Wph + ((size_t)(f * 64 + lane)) * 8);
            v8s bl = *(const v8s*)(Wpl + ((size_t)(f * 64 + lane)) * 8);
            acc[ti] = __builtin_amdgcn_mfma_f32_16x16x32_bf16(al, bh, acc[ti], 0, 0, 0);
            acc[ti] = __builtin_amdgcn_mfma_f32_16x16x32_bf16(ah, bl, acc[ti], 0, 0, 0);
            acc[ti] = __builtin_amdgcn_mfma_f32_16x16x32_bf16(ah, bh, acc[ti], 0, 0, 0);
        }
    }

    int rbase = base_row + w * 16 + quad * 4;
#pragma unroll
    for (int reg = 0; reg < 4; reg++) {
        int gr = rbase + reg;
        if (gr < M) {
            float di = dinv[gr];
#pragma unroll
            for (int ti = 0; ti < 8; ti++) {
                Cb[(size_t)gr * D + ti * 16 + m_l] = f2bf(di * acc[ti][reg]);
            }
        }
    }
}

// f32 [M][128] row-major A-tile -> split-bf16 LDS staging (shared by both GEMMs)
static __device__ __forceinline__ void stage_tile(uint16_t Ah[][LDA], uint16_t Al[][LDA],
                                                  const float* __restrict__ A,
                                                  int base_row, int M, int t) {
#pragma unroll
    for (int kk = 0; kk < 8; kk++) {
        int idx = kk * 256 + t;
        int r = idx >> 5;
        int c4 = idx & 31;
        int gr = base_row + r;
        float4 f = (gr < M) ? *(const float4*)(A + (size_t)gr * D + c4 * 4)
                            : make_float4(0.f, 0.f, 0.f, 0.f);
        uint16_t h0 = f2bf(f.x), h1 = f2bf(f.y), h2 = f2bf(f.z), h3 = f2bf(f.w);
        uint16_t l0 = f2bf(f.x - bf2f(h0)), l1 = f2bf(f.y - bf2f(h1));
        uint16_t l2 = f2bf(f.z - bf2f(h2)), l3 = f2bf(f.w - bf2f(h3));
        *(ushort4*)&Ah[r][c4 * 4] = make_ushort4(h0, h1, h2, h3);
        *(ushort4*)&Al[r][c4 * 4] = make_ushort4(l0, l1, l2, l3);
    }
}

// ---------------- fused: CSR fill (block-role split) + layer-1 GEMM ----------------

__global__ __launch_bounds__(256) void fillgemm_kernel(const int* __restrict__ row,
                                                       const int* __restrict__ col,
                                                       const int* __restrict__ rnk,
                                                       const int* __restrict__ offs,
                                                       int* __restrict__ adj, int E,
                                                       const float* __restrict__ A,
                                                       const uint16_t* __restrict__ Wph,
                                                       const uint16_t* __restrict__ Wpl,
                                                       const float* __restrict__ dinv,
                                                       uint16_t* __restrict__ Cb, int M,
                                                       int nbG) {
    __shared__ uint16_t Ah[64][LDA];
    __shared__ uint16_t Al[64][LDA];
    int t = threadIdx.x;

    if (blockIdx.x >= nbG) {   // ---- fill role (atomic-free scatter) ----
        int e = (blockIdx.x - nbG) * 256 + t;
        if (e < E) adj[offs[col[e]] + rnk[e]] = row[e];
        return;
    }

    int base_row = blockIdx.x * 64;
    stage_tile(Ah, Al, A, base_row, M, t);
    __syncthreads();
    gemm_body(Ah, Al, Wph, Wpl, dinv, Cb, base_row, M, t);
}

// ---------------- plain GEMM (layer 2: h -> xwb2) ----------------

__global__ __launch_bounds__(256) void gemm_kernel(const float* __restrict__ A,
                                                   const uint16_t* __restrict__ Wph,
                                                   const uint16_t* __restrict__ Wpl,
                                                   const float* __restrict__ dinv,
                                                   uint16_t* __restrict__ Cb, int M) {
    __shared__ uint16_t Ah[64][LDA];
    __shared__ uint16_t Al[64][LDA];
    int t = threadIdx.x;
    int base_row = blockIdx.x * 64;
    stage_tile(Ah, Al, A, base_row, M, t);
    __syncthreads();
    gemm_body(Ah, Al, Wph, Wpl, dinv, Cb, base_row, M, t);
}

// ---------------- aggregation, layer 1: TWO nodes per wave, full-row gather ----------
// Full-row uint32 loads (64 lanes x 4B = one 256 B row per instruction) — the fastest
// measured gather form (R1: ~3.3 TB/s vs 3.0 dual-row / 2.6 quartered). Two nodes per
// wave with an 8+8 interleaved main loop -> 16 row-loads (64 lines) in flight per wave
// at standalone-agg occupancy (the fused variant ran this at only 27-37% occupancy).

__global__ __launch_bounds__(256) void agg1_kernel(const uint32_t* __restrict__ xwb,
                                                   const int* __restrict__ adj,
                                                   const int* __restrict__ offs,
                                                   const float* __restrict__ dinv,
                                                   const float* __restrict__ bias,
                                                   float* __restrict__ hout, int n) {
    int wave = (int)((blockIdx.x * (size_t)blockDim.x + threadIdx.x) >> 6);
    int lane = threadIdx.x & 63;
    int i0 = wave * 2, i1 = wave * 2 + 1;
    if (i0 >= n) return;
    bool has1 = (i1 < n);

    float a0, a1, c0 = 0.f, c1 = 0.f;
    uint32_t su0 = xwb[(size_t)i0 * (D / 2) + lane];
    a0 = bf_lo(su0); a1 = bf_hi(su0);
    int jA = offs[i0], eA = offs[i0 + 1];
    int jB = 0, eB = 0;
    if (has1) {
        uint32_t su1 = xwb[(size_t)i1 * (D / 2) + lane];
        c0 = bf_lo(su1); c1 = bf_hi(su1);
        jB = offs[i1]; eB = offs[i1 + 1];
    }

    // interleaved main loop: 8 gathers per node, 16 rows in flight
    while (jA + 7 < eA && jB + 7 < eB) {
        int xx[8], yy[8];
#pragma unroll
        for (int q = 0; q < 8; q++) { xx[q] = adj[jA + q]; yy[q] = adj[jB + q]; }
        uint32_t uA[8], uB[8];
#pragma unroll
        for (int q = 0; q < 8; q++) {
            uA[q] = xwb[(size_t)xx[q] * (D / 2) + lane];
            uB[q] = xwb[(size_t)yy[q] * (D / 2) + lane];
        }
#pragma unroll
        for (int q = 0; q < 8; q++) {
            a0 += bf_lo(uA[q]); a1 += bf_hi(uA[q]);
            c0 += bf_lo(uB[q]); c1 += bf_hi(uB[q]);
        }
        jA += 8; jB += 8;
    }
    // drain A
    for (; jA + 7 < eA; jA += 8) {
        int xx[8]; uint32_t uA[8];
#pragma unroll
        for (int q = 0; q < 8; q++) xx[q] = adj[jA + q];
#pragma unroll
        for (int q = 0; q < 8; q++) uA[q] = xwb[(size_t)xx[q] * (D / 2) + lane];
#pragma unroll
        for (int q = 0; q < 8; q++) { a0 += bf_lo(uA[q]); a1 += bf_hi(uA[q]); }
    }
    for (; jA + 3 < eA; jA += 4) {
        int x0 = adj[jA], x1 = adj[jA + 1], x2 = adj[jA + 2], x3 = adj[jA + 3];
        uint32_t u0 = xwb[(size_t)x0 * (D / 2) + lane];
        uint32_t u1 = xwb[(size_t)x1 * (D / 2) + lane];
        uint32_t u2 = xwb[(size_t)x2 * (D / 2) + lane];
        uint32_t u3 = xwb[(size_t)x3 * (D / 2) + lane];
        a0 += bf_lo(u0); a1 += bf_hi(u0);
        a0 += bf_lo(u1); a1 += bf_hi(u1);
        a0 += bf_lo(u2); a1 += bf_hi(u2);
        a0 += bf_lo(u3); a1 += bf_hi(u3);
    }
    for (; jA < eA; jA++) {
        uint32_t u = xwb[(size_t)adj[jA] * (D / 2) + lane];
        a0 += bf_lo(u); a1 += bf_hi(u);
    }
    // drain B
    for (; jB + 7 < eB; jB += 8) {
        int yy[8]; uint32_t uB[8];
#pragma unroll
        for (int q = 0; q < 8; q++) yy[q] = adj[jB + q];
#pragma unroll
        for (int q = 0; q < 8; q++) uB[q] = xwb[(size_t)yy[q] * (D / 2) + lane];
#pragma unroll
        for (int q = 0; q < 8; q++) { c0 += bf_lo(uB[q]); c1 += bf_hi(uB[q]); }
    }
    for (; jB + 3 < eB; jB += 4) {
        int y0 = adj[jB], y1 = adj[jB + 1], y2 = adj[jB + 2], y3 = adj[jB + 3];
        uint32_t u0 = xwb[(size_t)y0 * (D / 2) + lane];
        uint32_t u1 = xwb[(size_t)y1 * (D / 2) + lane];
        uint32_t u2 = xwb[(size_t)y2 * (D / 2) + lane];
        uint32_t u3 = xwb[(size_t)y3 * (D / 2) + lane];
        c0 += bf_lo(u0); c1 += bf_hi(u0);
        c0 += bf_lo(u1); c1 += bf_hi(u1);
        c0 += bf_lo(u2); c1 += bf_hi(u2);
        c0 += bf_lo(u3); c1 += bf_hi(u3);
    }
    for (; jB < eB; jB++) {
        uint32_t u = xwb[(size_t)adj[jB] * (D / 2) + lane];
        c0 += bf_lo(u); c1 += bf_hi(u);
    }

    float2 bv = ((const float2*)bias)[lane];
    float di0 = dinv[i0];
    float o0 = fmaxf(fmaf(di0, a0, bv.x), 0.f);
    float o1 = fmaxf(fmaf(di0, a1, bv.y), 0.f);
    ((float2*)(hout + (size_t)i0 * D))[lane] = make_float2(o0, o1);
    if (has1) {
        float di1 = dinv[i1];
        float o2 = fmaxf(fmaf(di1, c0, bv.x), 0.f);
        float o3 = fmaxf(fmaf(di1, c1, bv.y), 0.f);
        ((float2*)(hout + (size_t)i1 * D))[lane] = make_float2(o2, o3);
    }
}

// ---------------- layer-2 aggregation + classifier precompute, TWO nodes per wave ----
// Same gather; epilogue computes both nodes' 8 classifier dot-products in-register
// (lane holds h[i][2*lane], h[i][2*lane+1]) and reduces 16 values with one 6-stage
// 64-wide butterfly — same shuffle cost PER NODE as the single-node version.

__global__ __launch_bounds__(256) void agg2pq_kernel(const uint32_t* __restrict__ xwb,
                                                     const int* __restrict__ adj,
                                                     const int* __restrict__ offs,
                                                     const float* __restrict__ dinv,
                                                     const float* __restrict__ bias,
                                                     const float* __restrict__ Wfc,
                                                     const float* __restrict__ bfc,
                                                     float* __restrict__ P1,
                                                     float* __restrict__ P2, int n) {
    int wave = (int)((blockIdx.x * (size_t)blockDim.x + threadIdx.x) >> 6);
    int lane = threadIdx.x & 63;
    int i0 = wave * 2, i1 = wave * 2 + 1;
    if (i0 >= n) return;
    bool has1 = (i1 < n);

    float a0, a1, c0 = 0.f, c1 = 0.f;
    uint32_t su0 = xwb[(size_t)i0 * (D / 2) + lane];
    a0 = bf_lo(su0); a1 = bf_hi(su0);
    int jA = offs[i0], eA = offs[i0 + 1];
    int jB = 0, eB = 0;
    if (has1) {
        uint32_t su1 = xwb[(size_t)i1 * (D / 2) + lane];
        c0 = bf_lo(su1); c1 = bf_hi(su1);
        jB = offs[i1]; eB = offs[i1 + 1];
    }

    while (jA + 7 < eA && jB + 7 < eB) {
        int xx[8], yy[8];
#pragma unroll
        for (int q = 0; q < 8; q++) { xx[q] = adj[jA + q]; yy[q] = adj[jB + q]; }
        uint32_t uA[8], uB[8];
#pragma unroll
        for (int q = 0; q < 8; q++) {
            uA[q] = xwb[(size_t)xx[q] * (D / 2) + lane];
            uB[q] = xwb[(size_t)yy[q] * (D / 2) + lane];
        }
#pragma unroll
        for (int q = 0; q < 8; q++) {
            a0 += bf_lo(uA[q]); a1 += bf_hi(uA[q]);
            c0 += bf_lo(uB[q]); c1 += bf_hi(uB[q]);
        }
        jA += 8; jB += 8;
    }
    for (; jA + 7 < eA; jA += 8) {
        int xx[8]; uint32_t uA[8];
#pragma unroll
        for (int q = 0; q < 8; q++) xx[q] = adj[jA + q];
#pragma unroll
        for (int q = 0; q < 8; q++) uA[q] = xwb[(size_t)xx[q] * (D / 2) + lane];
#pragma unroll
        for (int q = 0; q < 8; q++) { a0 += bf_lo(uA[q]); a1 += bf_hi(uA[q]); }
    }
    for (; jA + 3 < eA; jA += 4) {
        int x0 = adj[jA], x1 = adj[jA + 1], x2 = adj[jA + 2], x3 = adj[jA + 3];
        uint32_t u0 = xwb[(size_t)x0 * (D / 2) + lane];
        uint32_t u1 = xwb[(size_t)x1 * (D / 2) + lane];
        uint32_t u2 = xwb[(size_t)x2 * (D / 2) + lane];
        uint32_t u3 = xwb[(size_t)x3 * (D / 2) + lane];
        a0 += bf_lo(u0); a1 += bf_hi(u0);
        a0 += bf_lo(u1); a1 += bf_hi(u1);
        a0 += bf_lo(u2); a1 += bf_hi(u2);
        a0 += bf_lo(u3); a1 += bf_hi(u3);
    }
    for (; jA < eA; jA++) {
        uint32_t u = xwb[(size_t)adj[jA] * (D / 2) + lane];
        a0 += bf_lo(u); a1 += bf_hi(u);
    }
    for (; jB + 7 < eB; jB += 8) {
        int yy[8]; uint32_t uB[8];
#pragma unroll
        for (int q = 0; q < 8; q++) yy[q] = adj[jB + q];
#pragma unroll
        for (int q = 0; q < 8; q++) uB[q] = xwb[(size_t)yy[q] * (D / 2) + lane];
#pragma unroll
        for (int q = 0; q < 8; q++) { c0 += bf_lo(uB[q]); c1 += bf_hi(uB[q]); }
    }
    for (; jB + 3 < eB; jB += 4) {
        int y0 = adj[jB], y1 = adj[jB + 1], y2 = adj[jB + 2], y3 = adj[jB + 3];
        uint32_t u0 = xwb[(size_t)y0 * (D / 2) + lane];
        uint32_t u1 = xwb[(size_t)y1 * (D / 2) + lane];
        uint32_t u2 = xwb[(size_t)y2 * (D / 2) + lane];
        uint32_t u3 = xwb[(size_t)y3 * (D / 2) + lane];
        c0 += bf_lo(u0); c1 += bf_hi(u0);
        c0 += bf_lo(u1); c1 += bf_hi(u1);
        c0 += bf_lo(u2); c1 += bf_hi(u2);
        c0 += bf_lo(u3); c1 += bf_hi(u3);
    }
    for (; jB < eB; jB++) {
        uint32_t u = xwb[(size_t)adj[jB] * (D / 2) + lane];
        c0 += bf_lo(u); c1 += bf_hi(u);
    }

    float2 bv = ((const float2*)bias)[lane];
    float di0 = dinv[i0];
    float o0 = fmaxf(fmaf(di0, a0, bv.x), 0.f);
    float o1 = fmaxf(fmaf(di0, a1, bv.y), 0.f);
    float di1 = has1 ? dinv[i1] : 0.f;
    float o2 = fmaxf(fmaf(di1, c0, bv.x), 0.f);
    float o3 = fmaxf(fmaf(di1, c1, bv.y), 0.f);
    if (!has1) { o2 = 0.f; o3 = 0.f; }

    // classifier partials: lane holds h[i][2*lane], h[i][2*lane+1] for both nodes
    const float4* W4 = (const float4*)Wfc;          // Wfc is [256][4] row-major
    float4 wa = W4[2 * lane];
    float4 wb = W4[2 * lane + 1];
    float4 wc = W4[128 + 2 * lane];
    float4 wd = W4[129 + 2 * lane];
    float p0 = fmaf(o0, wa.x, o1 * wb.x), p1 = fmaf(o0, wa.y, o1 * wb.y);
    float p2 = fmaf(o0, wa.z, o1 * wb.z), p3 = fmaf(o0, wa.w, o1 * wb.w);
    float q0 = fmaf(o0, wc.x, o1 * wd.x), q1 = fmaf(o0, wc.y, o1 * wd.y);
    float q2 = fmaf(o0, wc.z, o1 * wd.z), q3 = fmaf(o0, wc.w, o1 * wd.w);
    float r0 = fmaf(o2, wa.x, o3 * wb.x), r1 = fmaf(o2, wa.y, o3 * wb.y);
    float r2 = fmaf(o2, wa.z, o3 * wb.z), r3 = fmaf(o2, wa.w, o3 * wb.w);
    float s0 = fmaf(o2, wc.x, o3 * wd.x), s1 = fmaf(o2, wc.y, o3 * wd.y);
    float s2 = fmaf(o2, wc.z, o3 * wd.z), s3 = fmaf(o2, wc.w, o3 * wd.w);
#pragma unroll
    for (int off = 1; off < 64; off <<= 1) {
        p0 += __shfl_xor(p0, off, 64);
        p1 += __shfl_xor(p1, off, 64);
        p2 += __shfl_xor(p2, off, 64);
        p3 += __shfl_xor(p3, off, 64);
        q0 += __shfl_xor(q0, off, 64);
        q1 += __shfl_xor(q1, off, 64);
        q2 += __shfl_xor(q2, off, 64);
        q3 += __shfl_xor(q3, off, 64);
        r0 += __shfl_xor(r0, off, 64);
        r1 += __shfl_xor(r1, off, 64);
        r2 += __shfl_xor(r2, off, 64);
        r3 += __shfl_xor(r3, off, 64);
        s0 += __shfl_xor(s0, off, 64);
        s1 += __shfl_xor(s1, off, 64);
        s2 += __shfl_xor(s2, off, 64);
        s3 += __shfl_xor(s3, off, 64);
    }
    if (lane == 0) {
        float4 bb = *(const float4*)bfc;
        *(float4*)(P1 + (size_t)i0 * 4) = make_float4(p0 + bb.x, p1 + bb.y, p2 + bb.z, p3 + bb.w);
        *(float4*)(P2 + (size_t)i0 * 4) = make_float4(q0, q1, q2, q3);
        if (has1) {
            *(float4*)(P1 + (size_t)i1 * 4) = make_float4(r0 + bb.x, r1 + bb.y, r2 + bb.z, r3 + bb.w);
            *(float4*)(P2 + (size_t)i1 * 4) = make_float4(s0, s1, s2, s3);
        }
    }
}

// ---------------- edge classifier: one THREAD per edge ----------------

__global__ __launch_bounds__(256) void edge2_kernel(const int* __restrict__ row,
                                                    const int* __restrict__ col,
                                                    const float* __restrict__ P1,
                                                    const float* __restrict__ P2,
                                                    float* __restrict__ out, int E) {
    int e = blockIdx.x * blockDim.x + threadIdx.x;
    if (e >= E) return;
    int r = row[e], c = col[e];
    float4 a = ((const float4*)P1)[r];
    float4 b = ((const float4*)P2)[c];
    float sx = a.x + b.x, sy = a.y + b.y, sz = a.z + b.z, sw = a.w + b.w;
    float m = fmaxf(fmaxf(sx, sy), fmaxf(sz, sw));
    float e0 = expf(sx - m), e1 = expf(sy - m), e2 = expf(sz - m), e3 = expf(sw - m);
    float lse = m + logf(e0 + e1 + e2 + e3);
    *(float4*)(out + (size_t)e * 4) = make_float4(sx - lse, sy - lse, sz - lse, sw - lse);
}

// ---------------- launch ----------------

extern "C" void kernel_launch(void* const* d_in, const int* in_sizes, int n_in,
                              void* d_out, int out_size, void* d_ws, size_t ws_size,
                              hipStream_t stream) {
    const float* x   = (const float*)d_in[0];
    const int*   ei  = (const int*)d_in[1];
    const float* W1  = (const float*)d_in[2];
    const float* b1  = (const float*)d_in[3];
    const float* W2  = (const float*)d_in[4];
    const float* b2  = (const float*)d_in[5];
    const float* Wfc = (const float*)d_in[6];
    const float* bfc = (const float*)d_in[7];
    float* out = (float*)d_out;

    int n = in_sizes[0] / D;        // 50000
    int E = in_sizes[1] / 2;        // 600000
    const int* row = ei;            // edge_index[0]
    const int* col = ei + E;        // edge_index[1]

    int nbScan = (n + SCAN_CHUNK - 1) / SCAN_CHUNK;   // 25

    // workspace layout (all segments 16B-aligned)
    uint16_t* xwb  = (uint16_t*)d_ws;                    // [n][128] bf16 (layer-1 xW, dinv-prescaled)
    uint16_t* xwb2 = xwb + (size_t)n * D;                // [n][128] bf16 (layer-2 xW, dinv-prescaled)
    float*    h    = (float*)(xwb2 + (size_t)n * D);     // [n][128] f32 (layer-1 output)
    int*      cnt  = (int*)(h + (size_t)n * D);          // n
    int*      offs = cnt + n;                            // n+1 (+pad)
    int*      bsum = offs + (n + 4);                     // 64
    int*      adj  = bsum + 64;                          // E
    int*      rnk  = adj + E;                            // E (edge rank within bucket)
    float*    dinv = (float*)(rnk + E);                  // n
    uint16_t* Wph  = (uint16_t*)(dinv + n);              // 2*16384 (layer-major)
    uint16_t* Wpl  = Wph + 2 * 16384;                    // 2*16384
    float*    P1   = (float*)(Wpl + 2 * 16384);          // n*4
    float*    P2   = P1 + (size_t)n * 4;                 // n*4

    int nb_e = (E + 255) / 256;
    int nbG  = (n + 63) / 64;
    int nWaves = (n + 1) / 2;                 // two nodes per wave
    int nbA  = (nWaves + 3) / 4;              // 4 waves per block

    // CSR count (+ W pack; rank captured from atomicAdd return)
    hipMemsetAsync(cnt, 0, (size_t)n * sizeof(int), stream);
    countpack_kernel<<<nb_e, 256, 0, stream>>>(col, cnt, rnk, E, W1, W2, Wph, Wpl);
    scanA_kernel<<<nbScan, 256, 0, stream>>>(cnt, bsum, dinv, n);
    scanC_kernel<<<nbScan, 256, 0, stream>>>(cnt, bsum, offs, n, nbScan);

    // fill (CSR scatter) runs concurrently with layer-1 GEMM in one grid
    fillgemm_kernel<<<nbG + nb_e, 256, 0, stream>>>(row, col, rnk, offs, adj, E,
                                                    x, Wph, Wpl, dinv, xwb, n, nbG);

    // layer-1 aggregation (two nodes/wave, full-row gather) -> h f32
    agg1_kernel<<<nbA, 256, 0, stream>>>((const uint32_t*)xwb, adj, offs, dinv, b1, h, n);

    // layer-2 GEMM
    gemm_kernel<<<nbG, 256, 0, stream>>>(h, Wph + 16384, Wpl + 16384, dinv, xwb2, n);

    // layer-2 aggregation + classifier precompute (two nodes/wave, full-row gather)
    agg2pq_kernel<<<nbA, 256, 0, stream>>>((const uint32_t*)xwb2, adj, offs, dinv, b2,
                                           Wfc, bfc, P1, P2, n);

    // edge classifier
    edge2_kernel<<<nb_e, 256, 0, stream>>>(row, col, P1, P2, out, E);
}